// Round 13
// baseline (58.293 us; speedup 1.0000x reference)
//
#include <hip/hip_runtime.h>
#include <hip/hip_bf16.h>
#include <cstdint>
#include <cstddef>

// B=8, W=32, H=32, C=64, NH=8, P=64, M=32, AH=512, S=W*H=1024
#define SB 8
#define SNH 8
#define SS 1024
#define SC 64

typedef __attribute__((ext_vector_type(8)))  short bf16x8;
typedef __attribute__((ext_vector_type(4)))  short bf16x4;
typedef __attribute__((ext_vector_type(4)))  float f32x4;
typedef __attribute__((ext_vector_type(16))) float f32x16;
typedef __attribute__((ext_vector_type(4)))  unsigned u32x4;

#define INVLN2 1.44269504088896f
#define QSCALE (0.125f * INVLN2)

static __device__ __forceinline__ short f2bf(float f) {
    __hip_bfloat16 h = __float2bfloat16(f);
    return __builtin_bit_cast(short, h);
}
static __device__ __forceinline__ float bf2f(short s) {
    return __builtin_bit_cast(float, (unsigned)((unsigned short)s) << 16);
}

static __device__ __forceinline__ bf16x8 cvt8(const float* __restrict__ p, float scl) {
    const float4 a = *(const float4*)p;
    const float4 b = *(const float4*)(p + 4);
    bf16x8 o;
    o[0] = f2bf(a.x * scl); o[1] = f2bf(a.y * scl); o[2] = f2bf(a.z * scl); o[3] = f2bf(a.w * scl);
    o[4] = f2bf(b.x * scl); o[5] = f2bf(b.y * scl); o[6] = f2bf(b.z * scl); o[7] = f2bf(b.w * scl);
    return o;
}
static __device__ __forceinline__ bf16x8 cvt8v(float4 a, float4 b) {
    bf16x8 o;
    o[0] = f2bf(a.x); o[1] = f2bf(a.y); o[2] = f2bf(a.z); o[3] = f2bf(a.w);
    o[4] = f2bf(b.x); o[5] = f2bf(b.y); o[6] = f2bf(b.z); o[7] = f2bf(b.w);
    return o;
}

static __device__ __forceinline__ unsigned pk2(float lo, float hi) {
    return (unsigned)(unsigned short)f2bf(lo) | ((unsigned)(unsigned short)f2bf(hi) << 16);
}

#if __has_builtin(__builtin_amdgcn_permlane32_swap)
typedef __attribute__((ext_vector_type(2))) unsigned uint2v;
static __device__ __forceinline__ void plswap(unsigned& a, unsigned& b) {
    uint2v r = __builtin_amdgcn_permlane32_swap(a, b, false, false);
    a = r[0]; b = r[1];
}
#else
static __device__ __forceinline__ void plswap(unsigned& a, unsigned& b) {
    asm volatile("v_permlane32_swap_b32 %0, %1" : "+v"(a), "+v"(b));
}
#endif

static __device__ __forceinline__ float xhalf_sum(float x) {
    unsigned a = __builtin_bit_cast(unsigned, x), b = a;
    plswap(a, b);
    return __builtin_bit_cast(float, a) + __builtin_bit_cast(float, b);
}

#define MFMA32(a, b, c) __builtin_amdgcn_mfma_f32_32x32x16_bf16((a), (b), (c), 0, 0, 0)

// D-layout (32x32) -> B-frag conversion: src[i] i=0..31 holds value at
// index (i&3)+8*((i>>2)&3)+4h+32*(i>>4); produces 4x bf16x8 B-frags.
static __device__ __forceinline__ void dlayout_to_bfrag(const float* src, bf16x8* dst) {
#pragma unroll
    for (int k = 0; k < 4; ++k) {
        const int base = (k >> 1) * 16 + (k & 1) * 8;
        unsigned w0 = pk2(src[base + 0], src[base + 1]);
        unsigned w2 = pk2(src[base + 4], src[base + 5]);
        plswap(w0, w2);
        unsigned w1 = pk2(src[base + 2], src[base + 3]);
        unsigned w3 = pk2(src[base + 6], src[base + 7]);
        plswap(w1, w3);
        u32x4 uw; uw[0] = w0; uw[1] = w1; uw[2] = w2; uw[3] = w3;
        dst[k] = __builtin_bit_cast(bf16x8, uw);
    }
}

// ---------------------------------------------------------------------------
// Kernel 1: prep1 — pos tables, wv->bf16, hid->hidB + V^T (one hid pass),
// and per-head composite matrices M_n = QSCALE*wq_n^T wk_n (+ bias vectors).
// blocks: [0,64) pos | [64,80) wvB | [80,208) hidB+VtB | [208,216) M_n.
// ---------------------------------------------------------------------------
__global__ __launch_bounds__(256) void prep1(
    const float* __restrict__ row_emb, const float* __restrict__ col_emb,
    const float* __restrict__ w_row,   const float* __restrict__ w_col,
    const float* __restrict__ w_v,  const float* __restrict__ w_q,
    const float* __restrict__ w_k,  const float* __restrict__ hid,
    const float* __restrict__ b_q,  const float* __restrict__ b_k,
    float* __restrict__ posRow, float* __restrict__ posCol,
    short* __restrict__ wvB, short* __restrict__ hidB, short* __restrict__ VtBw,
    short* __restrict__ MqBt, float* __restrict__ row0,
    float* __restrict__ vn, float* __restrict__ snv)
{
    const int bx = blockIdx.x;
    const int tid = threadIdx.x;
    __shared__ float T[64][65];

    if (bx < 64) {
        const int idx = bx * 256 + tid;     // 0..16383
        const int which = idx >> 13;
        const int r = idx & 8191;
        const int n = r >> 10;
        const int j = (r >> 5) & 31;
        const int l = r & 31;
        const float* emb = which ? col_emb : row_emb;
        const float* wgt = which ? w_col : w_row;
        const int e = l - j + 31;
        float acc = 0.f;
        for (int p = 0; p < 64; p += 4) {
            const float4 ev = *(const float4*)&emb[e * 64 + p];
            const float4 wv4 = *(const float4*)&wgt[n * 64 + p];
            acc += ev.x * wv4.x + ev.y * wv4.y + ev.z * wv4.z + ev.w * wv4.w;
        }
        (which ? posCol : posRow)[r] = acc * INVLN2;
    } else if (bx < 80) {
        const int t = (bx - 64) * 256 + tid;          // 0..4095
        *(bf16x8*)&wvB[t * 8] = cvt8(&w_v[t * 8], 1.0f);
    } else if (bx < 208) {
        // hid tile -> hidB (straight bf16) + VtBw (tile-major transpose)
        const int z = bx - 80;              // 0..127, batch b on XCD b (z&7)
        const int b = z & 7, kt = z >> 3;
        const int r  = tid >> 2;            // 0..63
        const int c0 = (tid & 3) * 16;
        const float* src = hid + (((size_t)b * 1024) + kt * 64 + r) * 64 + c0;
        const float4 f0 = ((const float4*)src)[0];
        const float4 f1 = ((const float4*)src)[1];
        const float4 f2 = ((const float4*)src)[2];
        const float4 f3 = ((const float4*)src)[3];
        T[r][c0 + 0] = f0.x; T[r][c0 + 1] = f0.y; T[r][c0 + 2] = f0.z; T[r][c0 + 3] = f0.w;
        T[r][c0 + 4] = f1.x; T[r][c0 + 5] = f1.y; T[r][c0 + 6] = f1.z; T[r][c0 + 7] = f1.w;
        T[r][c0 + 8] = f2.x; T[r][c0 + 9] = f2.y; T[r][c0 +10] = f2.z; T[r][c0 +11] = f2.w;
        T[r][c0 +12] = f3.x; T[r][c0 +13] = f3.y; T[r][c0 +14] = f3.z; T[r][c0 +15] = f3.w;
        short* hb = hidB + (((size_t)b * 1024) + kt * 64 + r) * 64 + c0;
        *(bf16x8*)(hb)     = cvt8v(f0, f1);
        *(bf16x8*)(hb + 8) = cvt8v(f2, f3);
        __syncthreads();
        short* tbase = VtBw + ((size_t)(b * 16 + kt)) * 4096;
#pragma unroll
        for (int it = 0; it < 2; ++it) {
            const int d  = (tid >> 3) + 32 * it;
            const int k0 = (tid & 7) * 8;
            bf16x8 o;
#pragma unroll
            for (int j = 0; j < 8; ++j) o[j] = f2bf(T[k0 + j][d]);
            *(bf16x8*)&tbase[d * 64 + k0] = o;
        }
    } else {
        // per-head composite: M_n, row0_n = bq@wk_n, vn = bk@wq_n, sn = bq.bk
        const int n = bx - 208;             // 0..7
        const int wv = tid >> 6;
        const int lane = tid & 63;
        if (wv == 0) {
            // MqBt[n][c2][c1] = M[c1][c2], M = QSCALE*wq^T wk
            const int h = lane >> 5, qc = lane & 31;
            bf16x8 afr[2][4], bfr[2][4];
#pragma unroll
            for (int ct = 0; ct < 2; ++ct)
#pragma unroll
                for (int k = 0; k < 4; ++k) {
                    bf16x8 oa, ob;
#pragma unroll
                    for (int j = 0; j < 8; ++j) {
                        const int a = 16 * k + 8 * h + j;
                        oa[j] = f2bf(w_q[(size_t)(n * 64 + a) * 64 + 32 * ct + qc] * QSCALE);
                        ob[j] = f2bf(w_k[(size_t)(n * 64 + a) * 64 + 32 * ct + qc]);
                    }
                    afr[ct][k] = oa; bfr[ct][k] = ob;
                }
#pragma unroll
            for (int ct1 = 0; ct1 < 2; ++ct1)
#pragma unroll
                for (int ctc = 0; ctc < 2; ++ctc) {
                    f32x16 d;
#pragma unroll
                    for (int i = 0; i < 16; ++i) d[i] = 0.f;
                    d = MFMA32(afr[ct1][0], bfr[ctc][0], d);
                    d = MFMA32(afr[ct1][1], bfr[ctc][1], d);
                    d = MFMA32(afr[ct1][2], bfr[ctc][2], d);
                    d = MFMA32(afr[ct1][3], bfr[ctc][3], d);
                    short* mb = MqBt + n * 4096 + (32 * ctc + qc) * 64 + 32 * ct1 + 4 * h;
#pragma unroll
                    for (int rg = 0; rg < 4; ++rg) {
                        bf16x4 ov;
                        ov[0] = f2bf(d[4 * rg + 0]); ov[1] = f2bf(d[4 * rg + 1]);
                        ov[2] = f2bf(d[4 * rg + 2]); ov[3] = f2bf(d[4 * rg + 3]);
                        *(bf16x4*)&mb[8 * rg] = ov;
                    }
                }
        } else if (wv == 1) {
            const int c2 = lane;
            float acc = 0.f;
            for (int a = 0; a < 64; ++a)
                acc += b_q[n * 64 + a] * w_k[(size_t)(n * 64 + a) * 64 + c2];
            row0[n * 64 + c2] = acc * QSCALE;
        } else if (wv == 2) {
            const int c1 = lane;
            float acc = 0.f;
            for (int a = 0; a < 64; ++a)
                acc += b_k[n * 64 + a] * w_q[(size_t)(n * 64 + a) * 64 + c1];
            vn[n * 64 + c1] = acc * QSCALE;
        } else {
            float p = b_q[n * 64 + lane] * b_k[n * 64 + lane];
#pragma unroll
            for (int o = 1; o < 64; o <<= 1) p += __shfl_xor(p, o);
            if (lane == 0) snv[n] = p * QSCALE;
        }
    }
}

// ---------------------------------------------------------------------------
// Kernel 2: MFMA flash attention, fused Q-projection, 4-buffer / 1-barrier-
// per-2-tiles pipeline.  Each barrier window: issue 2 tiles' loads (T14),
// run TWO independent compute chains (cross-tile MFMA/VALU interleave),
// write next buffers, barrier.  Barriers 15 -> 7.  setprio around MFMA
// clusters (T5: window now has wave role-diversity).  LDS 64 KB/block,
// 2 blocks/CU.  grid 512; batch b = XCD (orig&7).
// ---------------------------------------------------------------------------
__global__ __launch_bounds__(256, 2) void attn_mfma(
    const short* __restrict__ hidB, const short* __restrict__ VtBw,
    const short* __restrict__ MqBt, const float* __restrict__ row0,
    const float* __restrict__ vn,   const float* __restrict__ snv,
    const float* __restrict__ posRow, const float* __restrict__ posCol,
    short* __restrict__ hoB)
{
    const int orig = blockIdx.x;           // 0..511
    const int swzb = (orig & 7) * 64 + (orig >> 3);
    const int b    = swzb >> 6;
    const int n    = (swzb >> 3) & 7;
    const int qblk = swzb & 7;

    const int tid  = threadIdx.x;
    const int w    = tid >> 6;
    const int lane = tid & 63;
    const int h    = lane >> 5;            // lane half
    const int qc   = lane & 31;            // query column
    const int qt   = qblk * 4 + w;         // 0..31
    const int q    = qt * 32 + qc;
    const int swz  = qc & 7;

    __shared__ __align__(16) short Kb0[4096], Kb1[4096], Kb2[4096], Kb3[4096];
    __shared__ __align__(16) short Vb0[4096], Vb1[4096], Vb2[4096], Vb3[4096];

    // ---- fused Q-side projection ----
    bf16x8 qf[4];
    float cq;
    {
        const short* hrow = hidB + (((size_t)b * 1024) + q) * 64 + 8 * h;
        bf16x8 hq[4];
#pragma unroll
        for (int kk = 0; kk < 4; ++kk) hq[kk] = *(const bf16x8*)(hrow + 16 * kk);

        float aD[32];
#pragma unroll
        for (int ct = 0; ct < 2; ++ct) {
            f32x16 ci;
            const float* r0p = row0 + n * 64 + 32 * ct + 4 * h;
#pragma unroll
            for (int rg = 0; rg < 4; ++rg) {
                const float4 v = *(const float4*)(r0p + 8 * rg);
                ci[4 * rg + 0] = v.x; ci[4 * rg + 1] = v.y;
                ci[4 * rg + 2] = v.z; ci[4 * rg + 3] = v.w;
            }
            const short* mbase = MqBt + n * 4096 + (size_t)(32 * ct + qc) * 64 + 8 * h;
            ci = MFMA32(*(const bf16x8*)(mbase),      hq[0], ci);
            ci = MFMA32(*(const bf16x8*)(mbase + 16), hq[1], ci);
            ci = MFMA32(*(const bf16x8*)(mbase + 32), hq[2], ci);
            ci = MFMA32(*(const bf16x8*)(mbase + 48), hq[3], ci);
#pragma unroll
            for (int i = 0; i < 16; ++i) aD[16 * ct + i] = ci[i];
        }
        dlayout_to_bfrag(aD, qf);

        float part = 0.f;
#pragma unroll
        for (int kk = 0; kk < 4; ++kk) {
            const float4 v0 = *(const float4*)&vn[n * 64 + 16 * kk + 8 * h];
            const float4 v1 = *(const float4*)&vn[n * 64 + 16 * kk + 8 * h + 4];
            part += bf2f(hq[kk][0]) * v0.x + bf2f(hq[kk][1]) * v0.y +
                    bf2f(hq[kk][2]) * v0.z + bf2f(hq[kk][3]) * v0.w +
                    bf2f(hq[kk][4]) * v1.x + bf2f(hq[kk][5]) * v1.y +
                    bf2f(hq[kk][6]) * v1.z + bf2f(hq[kk][7]) * v1.w;
        }
        cq = xhalf_sum(part) + snv[n];
    }

    // posRow constants + cq fold (kt-invariant)
    float prowA[16];
    {
        const float* pr = posRow + (n * 32 + qc) * 32 + 4 * h;
#pragma unroll
        for (int rg = 0; rg < 4; ++rg) {
            const float4 v = *(const float4*)(pr + 8 * rg);
            prowA[4 * rg + 0] = v.x + cq; prowA[4 * rg + 1] = v.y + cq;
            prowA[4 * rg + 2] = v.z + cq; prowA[4 * rg + 3] = v.w + cq;
        }
    }
    const float* pcp = posCol + (n * 32 + qt) * 32;

    const short* Kbase = hidB + (size_t)b * 65536;          // [s][64] rows = keys
    const short* Vbase = VtBw + ((size_t)b * 16) * 4096;    // tile-major [kt][d][64]

    // staging geometry: thread handles 16B chunks (srow, c16) and (srow+32, c16)
    const int c16 = tid & 7;
    const int srow = tid >> 3;          // 0..31
    const int woffA = srow * 128 + ((c16 ^ (srow & 7)) << 4);
    const int woffB = (srow + 32) * 128 + ((c16 ^ (srow & 7)) << 4);
    const short* kp0 = Kbase + (size_t)srow * 64 + c16 * 8;
    const short* kp1 = Kbase + (size_t)(srow + 32) * 64 + c16 * 8;
    const short* vp0 = Vbase + (size_t)srow * 64 + c16 * 8;
    const short* vp1 = Vbase + (size_t)(srow + 32) * 64 + c16 * 8;

    float lsum = 0.f;                     // per-half partial; combined at end
    f32x16 oacc[2];
#pragma unroll
    for (int dt = 0; dt < 2; ++dt)
#pragma unroll
        for (int i = 0; i < 16; ++i) oacc[dt][i] = 0.f;

    auto compute = [&](int kt, const short* Ktc_s, const short* Vtc_s) {
        const char* Ktc = (const char*)Ktc_s;
        const char* Vtc = (const char*)Vtc_s;
        const float pc0 = pcp[2 * kt];
        const float pc1 = pcp[2 * kt + 1];

        bf16x8 kf[2][4];
#pragma unroll
        for (int ct = 0; ct < 2; ++ct) {
            const int rb = (32 * ct + qc) * 128;
#pragma unroll
            for (int k = 0; k < 4; ++k)
                kf[ct][k] = *(const bf16x8*)(Ktc + rb + (((2 * k + h) ^ swz) << 4));
        }

        __builtin_amdgcn_s_setprio(1);
        f32x16 sc[2];
#pragma unroll
        for (int ct = 0; ct < 2; ++ct) {
            const float pc = ct ? pc1 : pc0;
            f32x16 ci;
#pragma unroll
            for (int i = 0; i < 16; ++i) ci[i] = prowA[i] + pc;
            ci = MFMA32(kf[ct][0], qf[0], ci);
            ci = MFMA32(kf[ct][1], qf[1], ci);
            ci = MFMA32(kf[ct][2], qf[2], ci);
            sc[ct] = MFMA32(kf[ct][3], qf[3], ci);
        }
        __builtin_amdgcn_s_setprio(0);

        bf16x8 vf[2][4];
#pragma unroll
        for (int dt = 0; dt < 2; ++dt) {
            const int rb = (32 * dt + qc) * 128;
#pragma unroll
            for (int ks = 0; ks < 4; ++ks)
                vf[dt][ks] = *(const bf16x8*)(Vtc + rb + (((2 * ks + h) ^ swz) << 4));
        }

        // P = exp2(sc), fixed m = 0
        float p[32];
#pragma unroll
        for (int i = 0; i < 16; ++i) {
            p[i]      = __builtin_amdgcn_exp2f(sc[0][i]);
            p[16 + i] = __builtin_amdgcn_exp2f(sc[1][i]);
        }
        float s8[8];
#pragma unroll
        for (int i = 0; i < 8; ++i)
            s8[i] = (p[i] + p[i + 8]) + (p[16 + i] + p[24 + i]);
        lsum += ((s8[0] + s8[1]) + (s8[2] + s8[3])) +
                ((s8[4] + s8[5]) + (s8[6] + s8[7]));

        bf16x8 pfrag[4];
        dlayout_to_bfrag(p, pfrag);

        __builtin_amdgcn_s_setprio(1);
#pragma unroll
        for (int dt = 0; dt < 2; ++dt) {
            f32x16 oa = oacc[dt];
            oa = MFMA32(vf[dt][0], pfrag[0], oa);
            oa = MFMA32(vf[dt][1], pfrag[1], oa);
            oa = MFMA32(vf[dt][2], pfrag[2], oa);
            oacc[dt] = MFMA32(vf[dt][3], pfrag[3], oa);
        }
        __builtin_amdgcn_s_setprio(0);
    };

    // prologue: stage tiles 0,1 into set0 (Kb0/Vb0, Kb1/Vb1)
    {
        const float4 a0 = *(const float4*)kp0;
        const float4 a1 = *(const float4*)kp1;
        const float4 a2 = *(const float4*)vp0;
        const float4 a3 = *(const float4*)vp1;
        const float4 b0 = *(const float4*)(kp0 + 4096);
        const float4 b1 = *(const float4*)(kp1 + 4096);
        const float4 b2 = *(const float4*)(vp0 + 4096);
        const float4 b3 = *(const float4*)(vp1 + 4096);
        *(float4*)((char*)Kb0 + woffA) = a0;
        *(float4*)((char*)Kb0 + woffB) = a1;
        *(float4*)((char*)Vb0 + woffA) = a2;
        *(float4*)((char*)Vb0 + woffB) = a3;
        *(float4*)((char*)Kb1 + woffA) = b0;
        *(float4*)((char*)Kb1 + woffB) = b1;
        *(float4*)((char*)Vb1 + woffA) = b2;
        *(float4*)((char*)Vb1 + woffB) = b3;
    }
    __syncthreads();

    // main loop: 4 super-iters; each half = 2 tiles per barrier
#pragma unroll 1
    for (int j = 0; j < 4; ++j) {
        // half 1: compute tiles 4j,4j+1 from set0; stage 4j+2,4j+3 -> set1
        {
            const size_t oA = (size_t)(4 * j + 2) * 4096;
            const size_t oB = (size_t)(4 * j + 3) * 4096;
            const float4 a0 = *(const float4*)(kp0 + oA);
            const float4 a1 = *(const float4*)(kp1 + oA);
            const float4 a2 = *(const float4*)(vp0 + oA);
            const float4 a3 = *(const float4*)(vp1 + oA);
            const float4 b0 = *(const float4*)(kp0 + oB);
            const float4 b1 = *(const float4*)(kp1 + oB);
            const float4 b2 = *(const float4*)(vp0 + oB);
            const float4 b3 = *(const float4*)(vp1 + oB);
            compute(4 * j,     Kb0, Vb0);
            compute(4 * j + 1, Kb1, Vb1);
            *(float4*)((char*)Kb2 + woffA) = a0;
            *(float4*)((char*)Kb2 + woffB) = a1;
            *(float4*)((char*)Vb2 + woffA) = a2;
            *(float4*)((char*)Vb2 + woffB) = a3;
            *(float4*)((char*)Kb3 + woffA) = b0;
            *(float4*)((char*)Kb3 + woffB) = b1;
            *(float4*)((char*)Vb3 + woffA) = b2;
            *(float4*)((char*)Vb3 + woffB) = b3;
            __syncthreads();
        }
        // half 2: compute tiles 4j+2,4j+3 from set1; stage 4j+4,4j+5 -> set0
        if (j < 3) {
            const size_t oA = (size_t)(4 * j + 4) * 4096;
            const size_t oB = (size_t)(4 * j + 5) * 4096;
            const float4 a0 = *(const float4*)(kp0 + oA);
            const float4 a1 = *(const float4*)(kp1 + oA);
            const float4 a2 = *(const float4*)(vp0 + oA);
            const float4 a3 = *(const float4*)(vp1 + oA);
            const float4 b0 = *(const float4*)(kp0 + oB);
            const float4 b1 = *(const float4*)(kp1 + oB);
            const float4 b2 = *(const float4*)(vp0 + oB);
            const float4 b3 = *(const float4*)(vp1 + oB);
            compute(4 * j + 2, Kb2, Vb2);
            compute(4 * j + 3, Kb3, Vb3);
            *(float4*)((char*)Kb0 + woffA) = a0;
            *(float4*)((char*)Kb0 + woffB) = a1;
            *(float4*)((char*)Vb0 + woffA) = a2;
            *(float4*)((char*)Vb0 + woffB) = a3;
            *(float4*)((char*)Kb1 + woffA) = b0;
            *(float4*)((char*)Kb1 + woffB) = b1;
            *(float4*)((char*)Vb1 + woffA) = b2;
            *(float4*)((char*)Vb1 + woffB) = b3;
            __syncthreads();
        } else {
            compute(14, Kb2, Vb2);
            compute(15, Kb3, Vb3);
        }
    }

    // epilogue: combine lsum halves, d = 32dt + 8rg + 4h + (0..3)
    const float inv = 1.0f / xhalf_sum(lsum);
    short* orow = hoB + ((size_t)(b * 1024 + q)) * 512 + n * 64 + 4 * h;
#pragma unroll
    for (int dt = 0; dt < 2; ++dt)
#pragma unroll
        for (int rg = 0; rg < 4; ++rg) {
            bf16x4 ov;
            ov[0] = f2bf(oacc[dt][4 * rg + 0] * inv);
            ov[1] = f2bf(oacc[dt][4 * rg + 1] * inv);
            ov[2] = f2bf(oacc[dt][4 * rg + 2] * inv);
            ov[3] = f2bf(oacc[dt][4 * rg + 3] * inv);
            *(bf16x4*)&orow[32 * dt + 8 * rg] = ov;
        }
}

// ---------------------------------------------------------------------------
// Kernel 3: final projection via MFMA — 512 one-wave blocks, XCD-aligned.
// C[8192][64] = hoB[8192][512] @ wvB^T;  out[row][d] = C + bv[d].
// ---------------------------------------------------------------------------
__global__ __launch_bounds__(64) void v_proj(
    const short* __restrict__ hoB, const short* __restrict__ wvB,
    const float* __restrict__ bv, float* __restrict__ out)
{
    const int bo = blockIdx.x;                    // 0..511
    const int bx = (bo & 7) * 64 + (bo >> 3);     // 16-row tile index
    const int lane = threadIdx.x;
    const int g  = lane >> 4;
    const int qi = lane & 15;
    const int row0 = bx * 16;

    const short* arow = hoB + (size_t)(row0 + qi) * 512 + 8 * g;

    f32x4 acc[4];
#pragma unroll
    for (int ct = 0; ct < 4; ++ct) acc[ct] = (f32x4){0.f, 0.f, 0.f, 0.f};

#pragma unroll 4
    for (int ks = 0; ks < 16; ++ks) {
        const bf16x8 af = *(const bf16x8*)(arow + ks * 32);
#pragma unroll
        for (int ct = 0; ct < 4; ++ct) {
            const bf16x8 bfr = *(const bf16x8*)(wvB + (size_t)(16 * ct + qi) * 512 + ks * 32 + 8 * g);
            acc[ct] = __builtin_amdgcn_mfma_f32_16x16x32_bf16(af, bfr, acc[ct], 0, 0, 0);
        }
    }

#pragma unroll
    for (int ct = 0; ct < 4; ++ct) {
        const float bias = bv[16 * ct + qi];
#pragma unroll
        for (int r = 0; r < 4; ++r)
            out[(size_t)(row0 + 4 * g + r) * 64 + 16 * ct + qi] = acc[ct][r] + bias;
    }
}

// ---------------------------------------------------------------------------
extern "C" void kernel_launch(void* const* d_in, const int* in_sizes, int n_in,
                              void* d_out, int out_size, void* d_ws, size_t ws_size,
                              hipStream_t stream)
{
    const float* hid     = (const float*)d_in[0];
    const float* row_emb = (const float*)d_in[2];
    const float* col_emb = (const float*)d_in[3];
    const float* w_row   = (const float*)d_in[4];
    const float* w_col   = (const float*)d_in[5];
    const float* w_q     = (const float*)d_in[6];
    const float* b_q     = (const float*)d_in[7];
    const float* w_k     = (const float*)d_in[8];
    const float* b_k     = (const float*)d_in[9];
    const float* w_v     = (const float*)d_in[10];
    const float* b_v     = (const float*)d_in[11];
    float* out = (float*)d_out;

    // ws layout:
    // hidB 512K sh | VtB 512K sh | MqBt 32K sh | posRow 8K f32 | posCol 8K f32 |
    // row0 512 f32 | vn 512 f32 | sn 8 f32 | wvB 32K sh | hoB 4M sh
    short* hidB   = (short*)d_ws;
    short* VtBw   = hidB + (size_t)SB * SS * SC;
    short* MqBt   = VtBw + (size_t)SB * SS * SC;
    float* posRow = (float*)(MqBt + SNH * SC * SC);
    float* posCol = posRow + SNH * 32 * 32;
    float* row0   = posCol + SNH * 32 * 32;
    float* vn     = row0 + SNH * SC;
    float* snv    = vn + SNH * SC;
    short* wvB    = (short*)(snv + 8);
    short* hoB    = wvB + (size_t)SC * SNH * SC;

    prep1<<<216, 256, 0, stream>>>(row_emb, col_emb, w_row, w_col, w_v, w_q,
                                   w_k, hid, b_q, b_k,
                                   posRow, posCol, wvB, hidB, VtBw,
                                   MqBt, row0, vn, snv);
    attn_mfma<<<512, 256, 0, stream>>>(hidB, VtBw, MqBt, row0, vn, snv,
                                       posRow, posCol, hoB);
    v_proj<<<512, 64, 0, stream>>>(hoB, wvB, b_v, out);
}

// Round 14
// 54.004 us; speedup vs baseline: 1.0794x; 1.0794x over previous
//
#include <hip/hip_runtime.h>
#include <hip/hip_bf16.h>
#include <cstdint>
#include <cstddef>

// B=8, W=32, H=32, C=64, NH=8, P=64, M=32, AH=512, S=W*H=1024
#define SB 8
#define SNH 8
#define SS 1024
#define SC 64

typedef __attribute__((ext_vector_type(8)))  short bf16x8;
typedef __attribute__((ext_vector_type(4)))  short bf16x4;
typedef __attribute__((ext_vector_type(4)))  float f32x4;
typedef __attribute__((ext_vector_type(16))) float f32x16;
typedef __attribute__((ext_vector_type(4)))  unsigned u32x4;

#define INVLN2 1.44269504088896f
#define QSCALE (0.125f * INVLN2)

static __device__ __forceinline__ short f2bf(float f) {
    __hip_bfloat16 h = __float2bfloat16(f);
    return __builtin_bit_cast(short, h);
}
static __device__ __forceinline__ float bf2f(short s) {
    return __builtin_bit_cast(float, (unsigned)((unsigned short)s) << 16);
}

static __device__ __forceinline__ bf16x8 cvt8(const float* __restrict__ p, float scl) {
    const float4 a = *(const float4*)p;
    const float4 b = *(const float4*)(p + 4);
    bf16x8 o;
    o[0] = f2bf(a.x * scl); o[1] = f2bf(a.y * scl); o[2] = f2bf(a.z * scl); o[3] = f2bf(a.w * scl);
    o[4] = f2bf(b.x * scl); o[5] = f2bf(b.y * scl); o[6] = f2bf(b.z * scl); o[7] = f2bf(b.w * scl);
    return o;
}
static __device__ __forceinline__ bf16x8 cvt8v(float4 a, float4 b) {
    bf16x8 o;
    o[0] = f2bf(a.x); o[1] = f2bf(a.y); o[2] = f2bf(a.z); o[3] = f2bf(a.w);
    o[4] = f2bf(b.x); o[5] = f2bf(b.y); o[6] = f2bf(b.z); o[7] = f2bf(b.w);
    return o;
}

static __device__ __forceinline__ unsigned pk2(float lo, float hi) {
    return (unsigned)(unsigned short)f2bf(lo) | ((unsigned)(unsigned short)f2bf(hi) << 16);
}

#if __has_builtin(__builtin_amdgcn_permlane32_swap)
typedef __attribute__((ext_vector_type(2))) unsigned uint2v;
static __device__ __forceinline__ void plswap(unsigned& a, unsigned& b) {
    uint2v r = __builtin_amdgcn_permlane32_swap(a, b, false, false);
    a = r[0]; b = r[1];
}
#else
static __device__ __forceinline__ void plswap(unsigned& a, unsigned& b) {
    asm volatile("v_permlane32_swap_b32 %0, %1" : "+v"(a), "+v"(b));
}
#endif

static __device__ __forceinline__ float xhalf_sum(float x) {
    unsigned a = __builtin_bit_cast(unsigned, x), b = a;
    plswap(a, b);
    return __builtin_bit_cast(float, a) + __builtin_bit_cast(float, b);
}

#define MFMA32(a, b, c) __builtin_amdgcn_mfma_f32_32x32x16_bf16((a), (b), (c), 0, 0, 0)

// D-layout (32x32) -> B-frag conversion (verified P-path recipe).
static __device__ __forceinline__ void dlayout_to_bfrag(const float* src, bf16x8* dst) {
#pragma unroll
    for (int k = 0; k < 4; ++k) {
        const int base = (k >> 1) * 16 + (k & 1) * 8;
        unsigned w0 = pk2(src[base + 0], src[base + 1]);
        unsigned w2 = pk2(src[base + 4], src[base + 5]);
        plswap(w0, w2);
        unsigned w1 = pk2(src[base + 2], src[base + 3]);
        unsigned w3 = pk2(src[base + 6], src[base + 7]);
        plswap(w1, w3);
        u32x4 uw; uw[0] = w0; uw[1] = w1; uw[2] = w2; uw[3] = w3;
        dst[k] = __builtin_bit_cast(bf16x8, uw);
    }
}

// half-of-D-layout (16 values, one sc block) -> 2 B-frags
static __device__ __forceinline__ void dhalf_to_bfrag(const float* src, bf16x8* dst) {
#pragma unroll
    for (int k = 0; k < 2; ++k) {
        const int base = k * 8;
        unsigned w0 = pk2(src[base + 0], src[base + 1]);
        unsigned w2 = pk2(src[base + 4], src[base + 5]);
        plswap(w0, w2);
        unsigned w1 = pk2(src[base + 2], src[base + 3]);
        unsigned w3 = pk2(src[base + 6], src[base + 7]);
        plswap(w1, w3);
        u32x4 uw; uw[0] = w0; uw[1] = w1; uw[2] = w2; uw[3] = w3;
        dst[k] = __builtin_bit_cast(bf16x8, uw);
    }
}

// ---------------------------------------------------------------------------
// Kernel 1: prep1 — pos tables, wv->bf16, hid->hidB + V^T (one hid pass),
// and per-head composite matrices M_n = QSCALE*wq_n^T wk_n (+ bias vectors).
// blocks: [0,64) pos | [64,80) wvB | [80,208) hidB+VtB | [208,216) M_n.
// ---------------------------------------------------------------------------
__global__ __launch_bounds__(256) void prep1(
    const float* __restrict__ row_emb, const float* __restrict__ col_emb,
    const float* __restrict__ w_row,   const float* __restrict__ w_col,
    const float* __restrict__ w_v,  const float* __restrict__ w_q,
    const float* __restrict__ w_k,  const float* __restrict__ hid,
    const float* __restrict__ b_q,  const float* __restrict__ b_k,
    float* __restrict__ posRow, float* __restrict__ posCol,
    short* __restrict__ wvB, short* __restrict__ hidB, short* __restrict__ VtBw,
    short* __restrict__ MqBt, float* __restrict__ row0,
    float* __restrict__ vn, float* __restrict__ snv)
{
    const int bx = blockIdx.x;
    const int tid = threadIdx.x;
    __shared__ float T[64][65];

    if (bx < 64) {
        const int idx = bx * 256 + tid;     // 0..16383
        const int which = idx >> 13;
        const int r = idx & 8191;
        const int n = r >> 10;
        const int j = (r >> 5) & 31;
        const int l = r & 31;
        const float* emb = which ? col_emb : row_emb;
        const float* wgt = which ? w_col : w_row;
        const int e = l - j + 31;
        float acc = 0.f;
        for (int p = 0; p < 64; p += 4) {
            const float4 ev = *(const float4*)&emb[e * 64 + p];
            const float4 wv4 = *(const float4*)&wgt[n * 64 + p];
            acc += ev.x * wv4.x + ev.y * wv4.y + ev.z * wv4.z + ev.w * wv4.w;
        }
        (which ? posCol : posRow)[r] = acc * INVLN2;
    } else if (bx < 80) {
        const int t = (bx - 64) * 256 + tid;          // 0..4095
        *(bf16x8*)&wvB[t * 8] = cvt8(&w_v[t * 8], 1.0f);
    } else if (bx < 208) {
        // hid tile -> hidB (straight bf16) + VtBw (tile-major transpose)
        const int z = bx - 80;              // 0..127, batch b on XCD b (z&7)
        const int b = z & 7, kt = z >> 3;
        const int r  = tid >> 2;            // 0..63
        const int c0 = (tid & 3) * 16;
        const float* src = hid + (((size_t)b * 1024) + kt * 64 + r) * 64 + c0;
        const float4 f0 = ((const float4*)src)[0];
        const float4 f1 = ((const float4*)src)[1];
        const float4 f2 = ((const float4*)src)[2];
        const float4 f3 = ((const float4*)src)[3];
        T[r][c0 + 0] = f0.x; T[r][c0 + 1] = f0.y; T[r][c0 + 2] = f0.z; T[r][c0 + 3] = f0.w;
        T[r][c0 + 4] = f1.x; T[r][c0 + 5] = f1.y; T[r][c0 + 6] = f1.z; T[r][c0 + 7] = f1.w;
        T[r][c0 + 8] = f2.x; T[r][c0 + 9] = f2.y; T[r][c0 +10] = f2.z; T[r][c0 +11] = f2.w;
        T[r][c0 +12] = f3.x; T[r][c0 +13] = f3.y; T[r][c0 +14] = f3.z; T[r][c0 +15] = f3.w;
        short* hb = hidB + (((size_t)b * 1024) + kt * 64 + r) * 64 + c0;
        *(bf16x8*)(hb)     = cvt8v(f0, f1);
        *(bf16x8*)(hb + 8) = cvt8v(f2, f3);
        __syncthreads();
        short* tbase = VtBw + ((size_t)(b * 16 + kt)) * 4096;
#pragma unroll
        for (int it = 0; it < 2; ++it) {
            const int d  = (tid >> 3) + 32 * it;
            const int k0 = (tid & 7) * 8;
            bf16x8 o;
#pragma unroll
            for (int j = 0; j < 8; ++j) o[j] = f2bf(T[k0 + j][d]);
            *(bf16x8*)&tbase[d * 64 + k0] = o;
        }
    } else {
        // per-head composite: M_n, row0_n = bq@wk_n, vn = bk@wq_n, sn = bq.bk
        const int n = bx - 208;             // 0..7
        const int wv = tid >> 6;
        const int lane = tid & 63;
        if (wv == 0) {
            const int h = lane >> 5, qc = lane & 31;
            bf16x8 afr[2][4], bfr[2][4];
#pragma unroll
            for (int ct = 0; ct < 2; ++ct)
#pragma unroll
                for (int k = 0; k < 4; ++k) {
                    bf16x8 oa, ob;
#pragma unroll
                    for (int j = 0; j < 8; ++j) {
                        const int a = 16 * k + 8 * h + j;
                        oa[j] = f2bf(w_q[(size_t)(n * 64 + a) * 64 + 32 * ct + qc] * QSCALE);
                        ob[j] = f2bf(w_k[(size_t)(n * 64 + a) * 64 + 32 * ct + qc]);
                    }
                    afr[ct][k] = oa; bfr[ct][k] = ob;
                }
#pragma unroll
            for (int ct1 = 0; ct1 < 2; ++ct1)
#pragma unroll
                for (int ctc = 0; ctc < 2; ++ctc) {
                    f32x16 d;
#pragma unroll
                    for (int i = 0; i < 16; ++i) d[i] = 0.f;
                    d = MFMA32(afr[ct1][0], bfr[ctc][0], d);
                    d = MFMA32(afr[ct1][1], bfr[ctc][1], d);
                    d = MFMA32(afr[ct1][2], bfr[ctc][2], d);
                    d = MFMA32(afr[ct1][3], bfr[ctc][3], d);
                    short* mb = MqBt + n * 4096 + (32 * ctc + qc) * 64 + 32 * ct1 + 4 * h;
#pragma unroll
                    for (int rg = 0; rg < 4; ++rg) {
                        bf16x4 ov;
                        ov[0] = f2bf(d[4 * rg + 0]); ov[1] = f2bf(d[4 * rg + 1]);
                        ov[2] = f2bf(d[4 * rg + 2]); ov[3] = f2bf(d[4 * rg + 3]);
                        *(bf16x4*)&mb[8 * rg] = ov;
                    }
                }
        } else if (wv == 1) {
            const int c2 = lane;
            float acc = 0.f;
            for (int a = 0; a < 64; ++a)
                acc += b_q[n * 64 + a] * w_k[(size_t)(n * 64 + a) * 64 + c2];
            row0[n * 64 + c2] = acc * QSCALE;
        } else if (wv == 2) {
            const int c1 = lane;
            float acc = 0.f;
            for (int a = 0; a < 64; ++a)
                acc += b_k[n * 64 + a] * w_q[(size_t)(n * 64 + a) * 64 + c1];
            vn[n * 64 + c1] = acc * QSCALE;
        } else {
            float p = b_q[n * 64 + lane] * b_k[n * 64 + lane];
#pragma unroll
            for (int o = 1; o < 64; o <<= 1) p += __shfl_xor(p, o);
            if (lane == 0) snv[n] = p * QSCALE;
        }
    }
}

// ---------------------------------------------------------------------------
// Kernel 2: MFMA flash attention — split-K flash-decoding (fixed-m makes the
// combine exact: lsum/oacc just add).  512 threads = 8 waves: waves 0-3 do
// K-tiles 0-7, waves 4-7 do tiles 8-15 for the SAME q-tiles.  Per-wave code
// is the round-12 proven chain (one compute per window, reg-staged,
// double-buffered, XOR-swizzled).  Total waves 4096 -> 4 waves/SIMD
// (vs 2) if VGPR <= 128.  Epilogue: group B dumps oacc+lsum to LDS
// (stride 34 floats -> 2-way bank conflict, free), group A merges+stores.
// grid 512; batch b = XCD (orig&7).
// ---------------------------------------------------------------------------
__global__ __launch_bounds__(512, 2) void attn_mfma(
    const short* __restrict__ hidB, const short* __restrict__ VtBw,
    const short* __restrict__ MqBt, const float* __restrict__ row0,
    const float* __restrict__ vn,   const float* __restrict__ snv,
    const float* __restrict__ posRow, const float* __restrict__ posCol,
    short* __restrict__ hoB)
{
    const int orig = blockIdx.x;           // 0..511
    const int swzb = (orig & 7) * 64 + (orig >> 3);
    const int b    = swzb >> 6;
    const int n    = (swzb >> 3) & 7;
    const int qblk = swzb & 7;

    const int tid  = threadIdx.x;          // 0..511
    const int w    = tid >> 6;             // 0..7
    const int lane = tid & 63;
    const int grp  = tid >> 8;             // 0: K-tiles 0-7, 1: K-tiles 8-15
    const int h    = lane >> 5;            // lane half
    const int qc   = lane & 31;            // query column
    const int qt   = qblk * 4 + (w & 3);   // 0..31
    const int q    = qt * 32 + qc;
    const int swz  = qc & 7;

    __shared__ __align__(16) short lds[32768];   // 64 KB
    short* const Kst0 = lds + (size_t)grp * 16384;
    short* const Vst0 = Kst0 + 4096;
    short* const Kst1 = Kst0 + 8192;
    short* const Vst1 = Kst0 + 12288;

    // ---- fused Q-side projection (dup across the two K-groups, cheap) ----
    bf16x8 qf[4];
    float cq;
    {
        const short* hrow = hidB + (((size_t)b * 1024) + q) * 64 + 8 * h;
        bf16x8 hq[4];
#pragma unroll
        for (int kk = 0; kk < 4; ++kk) hq[kk] = *(const bf16x8*)(hrow + 16 * kk);

        float aD[32];
#pragma unroll
        for (int ct = 0; ct < 2; ++ct) {
            f32x16 ci;
            const float* r0p = row0 + n * 64 + 32 * ct + 4 * h;
#pragma unroll
            for (int rg = 0; rg < 4; ++rg) {
                const float4 v = *(const float4*)(r0p + 8 * rg);
                ci[4 * rg + 0] = v.x; ci[4 * rg + 1] = v.y;
                ci[4 * rg + 2] = v.z; ci[4 * rg + 3] = v.w;
            }
            const short* mbase = MqBt + n * 4096 + (size_t)(32 * ct + qc) * 64 + 8 * h;
            ci = MFMA32(*(const bf16x8*)(mbase),      hq[0], ci);
            ci = MFMA32(*(const bf16x8*)(mbase + 16), hq[1], ci);
            ci = MFMA32(*(const bf16x8*)(mbase + 32), hq[2], ci);
            ci = MFMA32(*(const bf16x8*)(mbase + 48), hq[3], ci);
#pragma unroll
            for (int i = 0; i < 16; ++i) aD[16 * ct + i] = ci[i];
        }
        dlayout_to_bfrag(aD, qf);

        float part = 0.f;
#pragma unroll
        for (int kk = 0; kk < 4; ++kk) {
            const float4 v0 = *(const float4*)&vn[n * 64 + 16 * kk + 8 * h];
            const float4 v1 = *(const float4*)&vn[n * 64 + 16 * kk + 8 * h + 4];
            part += bf2f(hq[kk][0]) * v0.x + bf2f(hq[kk][1]) * v0.y +
                    bf2f(hq[kk][2]) * v0.z + bf2f(hq[kk][3]) * v0.w +
                    bf2f(hq[kk][4]) * v1.x + bf2f(hq[kk][5]) * v1.y +
                    bf2f(hq[kk][6]) * v1.z + bf2f(hq[kk][7]) * v1.w;
        }
        cq = xhalf_sum(part) + snv[n];
    }

    // posRow constants + cq fold (kt-invariant)
    float prowA[16];
    {
        const float* pr = posRow + (n * 32 + qc) * 32 + 4 * h;
#pragma unroll
        for (int rg = 0; rg < 4; ++rg) {
            const float4 v = *(const float4*)(pr + 8 * rg);
            prowA[4 * rg + 0] = v.x + cq; prowA[4 * rg + 1] = v.y + cq;
            prowA[4 * rg + 2] = v.z + cq; prowA[4 * rg + 3] = v.w + cq;
        }
    }
    const float* pcp = posCol + (n * 32 + qt) * 32;

    // K/V bases offset by my group's 8-tile half
    const short* Kbase = hidB + (size_t)b * 65536 + (size_t)grp * 8 * 4096;
    const short* Vbase = VtBw + (size_t)b * 65536 + (size_t)grp * 8 * 4096;

    // staging geometry within my group's 256 threads
    const int st   = tid & 255;
    const int c16  = st & 7;
    const int srow = st >> 3;           // 0..31
    const int woffA = srow * 128 + ((c16 ^ (srow & 7)) << 4);
    const int woffB = (srow + 32) * 128 + ((c16 ^ (srow & 7)) << 4);
    const short* kp0 = Kbase + (size_t)srow * 64 + c16 * 8;
    const short* kp1 = Kbase + (size_t)(srow + 32) * 64 + c16 * 8;
    const short* vp0 = Vbase + (size_t)srow * 64 + c16 * 8;
    const short* vp1 = Vbase + (size_t)(srow + 32) * 64 + c16 * 8;

    float lsum = 0.f;                     // per-half partial (cross-half at end)
    f32x16 oacc[2];
#pragma unroll
    for (int dt = 0; dt < 2; ++dt)
#pragma unroll
        for (int i = 0; i < 16; ++i) oacc[dt][i] = 0.f;

    // compute: sc blocks sequenced (ct0 fully, then ct1) to trim live temps
    auto compute = [&](int kt, const short* Ktc_s, const short* Vtc_s) {
        const char* Ktc = (const char*)Ktc_s;
        const char* Vtc = (const char*)Vtc_s;
        const float pcv[2] = {pcp[2 * kt], pcp[2 * kt + 1]};

        bf16x8 pfrag[4];
#pragma unroll
        for (int ct = 0; ct < 2; ++ct) {
            bf16x8 kf[4];
            const int rb = (32 * ct + qc) * 128;
#pragma unroll
            for (int k = 0; k < 4; ++k)
                kf[k] = *(const bf16x8*)(Ktc + rb + (((2 * k + h) ^ swz) << 4));

            f32x16 ci;
#pragma unroll
            for (int i = 0; i < 16; ++i) ci[i] = prowA[i] + pcv[ct];
            ci = MFMA32(kf[0], qf[0], ci);
            ci = MFMA32(kf[1], qf[1], ci);
            ci = MFMA32(kf[2], qf[2], ci);
            ci = MFMA32(kf[3], qf[3], ci);

            float p[16];
#pragma unroll
            for (int i = 0; i < 16; ++i) p[i] = __builtin_amdgcn_exp2f(ci[i]);
            float s8[8];
#pragma unroll
            for (int i = 0; i < 8; ++i) s8[i] = p[i] + p[i + 8];
            lsum += ((s8[0] + s8[1]) + (s8[2] + s8[3])) +
                    ((s8[4] + s8[5]) + (s8[6] + s8[7]));
            dhalf_to_bfrag(p, &pfrag[2 * ct]);
        }

        bf16x8 vf[2][4];
#pragma unroll
        for (int dt = 0; dt < 2; ++dt) {
            const int rb = (32 * dt + qc) * 128;
#pragma unroll
            for (int ks = 0; ks < 4; ++ks)
                vf[dt][ks] = *(const bf16x8*)(Vtc + rb + (((2 * ks + h) ^ swz) << 4));
        }
#pragma unroll
        for (int dt = 0; dt < 2; ++dt) {
            f32x16 oa = oacc[dt];
            oa = MFMA32(vf[dt][0], pfrag[0], oa);
            oa = MFMA32(vf[dt][1], pfrag[1], oa);
            oa = MFMA32(vf[dt][2], pfrag[2], oa);
            oacc[dt] = MFMA32(vf[dt][3], pfrag[3], oa);
        }
    };

    const int kt0a = grp * 8;   // my group's first absolute tile

    // prologue: stage my group's tile 0 into buf0
    {
        const float4 a0 = *(const float4*)kp0;
        const float4 a1 = *(const float4*)kp1;
        const float4 a2 = *(const float4*)vp0;
        const float4 a3 = *(const float4*)vp1;
        *(float4*)((char*)Kst0 + woffA) = a0;
        *(float4*)((char*)Kst0 + woffB) = a1;
        *(float4*)((char*)Vst0 + woffA) = a2;
        *(float4*)((char*)Vst0 + woffB) = a3;
    }
    __syncthreads();

#pragma unroll 1
    for (int pr = 0; pr < 4; ++pr) {
        const int j0 = 2 * pr, j1 = j0 + 1;
        // iter j0 (buf0): prefetch j0+1, compute, write buf1, barrier
        {
            const size_t o = (size_t)(j0 + 1) * 4096;
            const float4 a0 = *(const float4*)(kp0 + o);
            const float4 a1 = *(const float4*)(kp1 + o);
            const float4 a2 = *(const float4*)(vp0 + o);
            const float4 a3 = *(const float4*)(vp1 + o);
            compute(kt0a + j0, Kst0, Vst0);
            *(float4*)((char*)Kst1 + woffA) = a0;
            *(float4*)((char*)Kst1 + woffB) = a1;
            *(float4*)((char*)Vst1 + woffA) = a2;
            *(float4*)((char*)Vst1 + woffB) = a3;
            __syncthreads();
        }
        // iter j1 (buf1): prefetch j1+1 unless last, compute, write buf0
        if (j1 < 7) {
            const size_t o = (size_t)(j1 + 1) * 4096;
            const float4 a0 = *(const float4*)(kp0 + o);
            const float4 a1 = *(const float4*)(kp1 + o);
            const float4 a2 = *(const float4*)(vp0 + o);
            const float4 a3 = *(const float4*)(vp1 + o);
            compute(kt0a + j1, Kst1, Vst1);
            *(float4*)((char*)Kst0 + woffA) = a0;
            *(float4*)((char*)Kst0 + woffB) = a1;
            *(float4*)((char*)Vst0 + woffA) = a2;
            *(float4*)((char*)Vst0 + woffB) = a3;
            __syncthreads();
        } else {
            compute(kt0a + j1, Kst1, Vst1);
        }
    }

    // ---- split-K combine (fixed-m: plain adds) ----
    __syncthreads();                       // all compute reads done; lds reusable
    float* cb = (float*)lds;
    const int slot = ((w & 3) * 64 + lane) * 34;   // stride 34: 2-way conflict (free)
    if (grp == 1) {
#pragma unroll
        for (int i = 0; i < 16; ++i) { cb[slot + i] = oacc[0][i]; cb[slot + 16 + i] = oacc[1][i]; }
        cb[slot + 32] = lsum;
    }
    __syncthreads();
    if (grp == 0) {
#pragma unroll
        for (int i = 0; i < 16; ++i) { oacc[0][i] += cb[slot + i]; oacc[1][i] += cb[slot + 16 + i]; }
        lsum += cb[slot + 32];

        const float inv = 1.0f / xhalf_sum(lsum);
        short* orow = hoB + ((size_t)(b * 1024 + q)) * 512 + n * 64 + 4 * h;
#pragma unroll
        for (int dt = 0; dt < 2; ++dt)
#pragma unroll
            for (int rg = 0; rg < 4; ++rg) {
                bf16x4 ov;
                ov[0] = f2bf(oacc[dt][4 * rg + 0] * inv);
                ov[1] = f2bf(oacc[dt][4 * rg + 1] * inv);
                ov[2] = f2bf(oacc[dt][4 * rg + 2] * inv);
                ov[3] = f2bf(oacc[dt][4 * rg + 3] * inv);
                *(bf16x4*)&orow[32 * dt + 8 * rg] = ov;
            }
    }
}

// ---------------------------------------------------------------------------
// Kernel 3: final projection via MFMA — 512 one-wave blocks, XCD-aligned.
// C[8192][64] = hoB[8192][512] @ wvB^T;  out[row][d] = C + bv[d].
// ---------------------------------------------------------------------------
__global__ __launch_bounds__(64) void v_proj(
    const short* __restrict__ hoB, const short* __restrict__ wvB,
    const float* __restrict__ bv, float* __restrict__ out)
{
    const int bo = blockIdx.x;                    // 0..511
    const int bx = (bo & 7) * 64 + (bo >> 3);     // 16-row tile index
    const int lane = threadIdx.x;
    const int g  = lane >> 4;
    const int qi = lane & 15;
    const int row0 = bx * 16;

    const short* arow = hoB + (size_t)(row0 + qi) * 512 + 8 * g;

    f32x4 acc[4];
#pragma unroll
    for (int ct = 0; ct < 4; ++ct) acc[ct] = (f32x4){0.f, 0.f, 0.f, 0.f};

#pragma unroll 4
    for (int ks = 0; ks < 16; ++ks) {
        const bf16x8 af = *(const bf16x8*)(arow + ks * 32);
#pragma unroll
        for (int ct = 0; ct < 4; ++ct) {
            const bf16x8 bfr = *(const bf16x8*)(wvB + (size_t)(16 * ct + qi) * 512 + ks * 32 + 8 * g);
            acc[ct] = __builtin_amdgcn_mfma_f32_16x16x32_bf16(af, bfr, acc[ct], 0, 0, 0);
        }
    }

#pragma unroll
    for (int ct = 0; ct < 4; ++ct) {
        const float bias = bv[16 * ct + qi];
#pragma unroll
        for (int r = 0; r < 4; ++r)
            out[(size_t)(row0 + 4 * g + r) * 64 + 16 * ct + qi] = acc[ct][r] + bias;
    }
}

// ---------------------------------------------------------------------------
extern "C" void kernel_launch(void* const* d_in, const int* in_sizes, int n_in,
                              void* d_out, int out_size, void* d_ws, size_t ws_size,
                              hipStream_t stream)
{
    const float* hid     = (const float*)d_in[0];
    const float* row_emb = (const float*)d_in[2];
    const float* col_emb = (const float*)d_in[3];
    const float* w_row   = (const float*)d_in[4];
    const float* w_col   = (const float*)d_in[5];
    const float* w_q     = (const float*)d_in[6];
    const float* b_q     = (const float*)d_in[7];
    const float* w_k     = (const float*)d_in[8];
    const float* b_k     = (const float*)d_in[9];
    const float* w_v     = (const float*)d_in[10];
    const float* b_v     = (const float*)d_in[11];
    float* out = (float*)d_out;

    // ws layout:
    // hidB 512K sh | VtB 512K sh | MqBt 32K sh | posRow 8K f32 | posCol 8K f32 |
    // row0 512 f32 | vn 512 f32 | sn 8 f32 | wvB 32K sh | hoB 4M sh
    short* hidB   = (short*)d_ws;
    short* VtBw   = hidB + (size_t)SB * SS * SC;
    short* MqBt   = VtBw + (size_t)SB * SS * SC;
    float* posRow = (float*)(MqBt + SNH * SC * SC);
    float* posCol = posRow + SNH * 32 * 32;
    float* row0   = posCol + SNH * 32 * 32;
    float* vn     = row0 + SNH * SC;
    float* snv    = vn + SNH * SC;
    short* wvB    = (short*)(snv + 8);
    short* hoB    = wvB + (size_t)SC * SNH * SC;

    prep1<<<216, 256, 0, stream>>>(row_emb, col_emb, w_row, w_col, w_v, w_q,
                                   w_k, hid, b_q, b_k,
                                   posRow, posCol, wvB, hidB, VtBw,
                                   MqBt, row0, vn, snv);
    attn_mfma<<<512, 512, 0, stream>>>(hidB, VtBw, MqBt, row0, vn, snv,
                                       posRow, posCol, hoB);
    v_proj<<<512, 64, 0, stream>>>(hoB, wvB, b_v, out);
}

// Round 15
// 39.567 us; speedup vs baseline: 1.4733x; 1.3649x over previous
//
#include <hip/hip_runtime.h>
#include <hip/hip_bf16.h>
#include <cstdint>
#include <cstddef>

// B=8, W=32, H=32, C=64, NH=8, P=64, M=32, AH=512, S=W*H=1024
#define SB 8
#define SNH 8
#define SS 1024
#define SC 64

typedef __attribute__((ext_vector_type(8)))  short bf16x8;
typedef __attribute__((ext_vector_type(4)))  short bf16x4;
typedef __attribute__((ext_vector_type(4)))  float f32x4;
typedef __attribute__((ext_vector_type(16))) float f32x16;
typedef __attribute__((ext_vector_type(4)))  unsigned u32x4;

#define INVLN2 1.44269504088896f
#define QSCALE (0.125f * INVLN2)

static __device__ __forceinline__ short f2bf(float f) {
    __hip_bfloat16 h = __float2bfloat16(f);
    return __builtin_bit_cast(short, h);
}
static __device__ __forceinline__ float bf2f(short s) {
    return __builtin_bit_cast(float, (unsigned)((unsigned short)s) << 16);
}

static __device__ __forceinline__ bf16x8 cvt8(const float* __restrict__ p, float scl) {
    const float4 a = *(const float4*)p;
    const float4 b = *(const float4*)(p + 4);
    bf16x8 o;
    o[0] = f2bf(a.x * scl); o[1] = f2bf(a.y * scl); o[2] = f2bf(a.z * scl); o[3] = f2bf(a.w * scl);
    o[4] = f2bf(b.x * scl); o[5] = f2bf(b.y * scl); o[6] = f2bf(b.z * scl); o[7] = f2bf(b.w * scl);
    return o;
}
static __device__ __forceinline__ bf16x8 cvt8v(float4 a, float4 b) {
    bf16x8 o;
    o[0] = f2bf(a.x); o[1] = f2bf(a.y); o[2] = f2bf(a.z); o[3] = f2bf(a.w);
    o[4] = f2bf(b.x); o[5] = f2bf(b.y); o[6] = f2bf(b.z); o[7] = f2bf(b.w);
    return o;
}

static __device__ __forceinline__ unsigned pk2(float lo, float hi) {
    return (unsigned)(unsigned short)f2bf(lo) | ((unsigned)(unsigned short)f2bf(hi) << 16);
}

#if __has_builtin(__builtin_amdgcn_permlane32_swap)
typedef __attribute__((ext_vector_type(2))) unsigned uint2v;
static __device__ __forceinline__ void plswap(unsigned& a, unsigned& b) {
    uint2v r = __builtin_amdgcn_permlane32_swap(a, b, false, false);
    a = r[0]; b = r[1];
}
#else
static __device__ __forceinline__ void plswap(unsigned& a, unsigned& b) {
    asm volatile("v_permlane32_swap_b32 %0, %1" : "+v"(a), "+v"(b));
}
#endif

static __device__ __forceinline__ float xhalf_sum(float x) {
    unsigned a = __builtin_bit_cast(unsigned, x), b = a;
    plswap(a, b);
    return __builtin_bit_cast(float, a) + __builtin_bit_cast(float, b);
}

#define MFMA32(a, b, c) __builtin_amdgcn_mfma_f32_32x32x16_bf16((a), (b), (c), 0, 0, 0)

// D-layout (32x32) -> B-frag conversion (verified P-path recipe).
// src[i] holds value at k-dim index (i&3)+8*((i>>2)&3)+4h+32*(i>>4), col qc.
static __device__ __forceinline__ void dlayout_to_bfrag(const float* src, bf16x8* dst) {
#pragma unroll
    for (int k = 0; k < 4; ++k) {
        const int base = (k >> 1) * 16 + (k & 1) * 8;
        unsigned w0 = pk2(src[base + 0], src[base + 1]);
        unsigned w2 = pk2(src[base + 4], src[base + 5]);
        plswap(w0, w2);
        unsigned w1 = pk2(src[base + 2], src[base + 3]);
        unsigned w3 = pk2(src[base + 6], src[base + 7]);
        plswap(w1, w3);
        u32x4 uw; uw[0] = w0; uw[1] = w1; uw[2] = w2; uw[3] = w3;
        dst[k] = __builtin_bit_cast(bf16x8, uw);
    }
}

// half-of-D-layout (16 values, one sc block) -> 2 B-frags
static __device__ __forceinline__ void dhalf_to_bfrag(const float* src, bf16x8* dst) {
#pragma unroll
    for (int k = 0; k < 2; ++k) {
        const int base = k * 8;
        unsigned w0 = pk2(src[base + 0], src[base + 1]);
        unsigned w2 = pk2(src[base + 4], src[base + 5]);
        plswap(w0, w2);
        unsigned w1 = pk2(src[base + 2], src[base + 3]);
        unsigned w3 = pk2(src[base + 6], src[base + 7]);
        plswap(w1, w3);
        u32x4 uw; uw[0] = w0; uw[1] = w1; uw[2] = w2; uw[3] = w3;
        dst[k] = __builtin_bit_cast(bf16x8, uw);
    }
}

// ---------------------------------------------------------------------------
// Kernel 1: prep1 — pos tables, wv->bf16, hid->hidB + V^T (one hid pass),
// and per-head composite matrices M_n = QSCALE*wq_n^T wk_n (+ bias vectors).
// blocks: [0,64) pos | [64,80) wvB | [80,208) hidB+VtB | [208,216) M_n.
// ---------------------------------------------------------------------------
__global__ __launch_bounds__(256) void prep1(
    const float* __restrict__ row_emb, const float* __restrict__ col_emb,
    const float* __restrict__ w_row,   const float* __restrict__ w_col,
    const float* __restrict__ w_v,  const float* __restrict__ w_q,
    const float* __restrict__ w_k,  const float* __restrict__ hid,
    const float* __restrict__ b_q,  const float* __restrict__ b_k,
    float* __restrict__ posRow, float* __restrict__ posCol,
    short* __restrict__ wvB, short* __restrict__ hidB, short* __restrict__ VtBw,
    short* __restrict__ MqBt, float* __restrict__ row0,
    float* __restrict__ vn, float* __restrict__ snv)
{
    const int bx = blockIdx.x;
    const int tid = threadIdx.x;
    __shared__ float T[64][65];

    if (bx < 64) {
        const int idx = bx * 256 + tid;     // 0..16383
        const int which = idx >> 13;
        const int r = idx & 8191;
        const int n = r >> 10;
        const int j = (r >> 5) & 31;
        const int l = r & 31;
        const float* emb = which ? col_emb : row_emb;
        const float* wgt = which ? w_col : w_row;
        const int e = l - j + 31;
        float acc = 0.f;
        for (int p = 0; p < 64; p += 4) {
            const float4 ev = *(const float4*)&emb[e * 64 + p];
            const float4 wv4 = *(const float4*)&wgt[n * 64 + p];
            acc += ev.x * wv4.x + ev.y * wv4.y + ev.z * wv4.z + ev.w * wv4.w;
        }
        (which ? posCol : posRow)[r] = acc * INVLN2;
    } else if (bx < 80) {
        const int t = (bx - 64) * 256 + tid;          // 0..4095
        *(bf16x8*)&wvB[t * 8] = cvt8(&w_v[t * 8], 1.0f);
    } else if (bx < 208) {
        // hid tile -> hidB (straight bf16) + VtBw (tile-major transpose)
        const int z = bx - 80;              // 0..127, batch b on XCD b (z&7)
        const int b = z & 7, kt = z >> 3;
        const int r  = tid >> 2;            // 0..63
        const int c0 = (tid & 3) * 16;
        const float* src = hid + (((size_t)b * 1024) + kt * 64 + r) * 64 + c0;
        const float4 f0 = ((const float4*)src)[0];
        const float4 f1 = ((const float4*)src)[1];
        const float4 f2 = ((const float4*)src)[2];
        const float4 f3 = ((const float4*)src)[3];
        T[r][c0 + 0] = f0.x; T[r][c0 + 1] = f0.y; T[r][c0 + 2] = f0.z; T[r][c0 + 3] = f0.w;
        T[r][c0 + 4] = f1.x; T[r][c0 + 5] = f1.y; T[r][c0 + 6] = f1.z; T[r][c0 + 7] = f1.w;
        T[r][c0 + 8] = f2.x; T[r][c0 + 9] = f2.y; T[r][c0 +10] = f2.z; T[r][c0 +11] = f2.w;
        T[r][c0 +12] = f3.x; T[r][c0 +13] = f3.y; T[r][c0 +14] = f3.z; T[r][c0 +15] = f3.w;
        short* hb = hidB + (((size_t)b * 1024) + kt * 64 + r) * 64 + c0;
        *(bf16x8*)(hb)     = cvt8v(f0, f1);
        *(bf16x8*)(hb + 8) = cvt8v(f2, f3);
        __syncthreads();
        short* tbase = VtBw + ((size_t)(b * 16 + kt)) * 4096;
#pragma unroll
        for (int it = 0; it < 2; ++it) {
            const int d  = (tid >> 3) + 32 * it;
            const int k0 = (tid & 7) * 8;
            bf16x8 o;
#pragma unroll
            for (int j = 0; j < 8; ++j) o[j] = f2bf(T[k0 + j][d]);
            *(bf16x8*)&tbase[d * 64 + k0] = o;
        }
    } else {
        // per-head composite: M_n, row0_n = bq@wk_n, vn = bk@wq_n, sn = bq.bk
        const int n = bx - 208;             // 0..7
        const int wv = tid >> 6;
        const int lane = tid & 63;
        if (wv == 0) {
            const int h = lane >> 5, qc = lane & 31;
            bf16x8 afr[2][4], bfr[2][4];
#pragma unroll
            for (int ct = 0; ct < 2; ++ct)
#pragma unroll
                for (int k = 0; k < 4; ++k) {
                    bf16x8 oa, ob;
#pragma unroll
                    for (int j = 0; j < 8; ++j) {
                        const int a = 16 * k + 8 * h + j;
                        oa[j] = f2bf(w_q[(size_t)(n * 64 + a) * 64 + 32 * ct + qc] * QSCALE);
                        ob[j] = f2bf(w_k[(size_t)(n * 64 + a) * 64 + 32 * ct + qc]);
                    }
                    afr[ct][k] = oa; bfr[ct][k] = ob;
                }
#pragma unroll
            for (int ct1 = 0; ct1 < 2; ++ct1)
#pragma unroll
                for (int ctc = 0; ctc < 2; ++ctc) {
                    f32x16 d;
#pragma unroll
                    for (int i = 0; i < 16; ++i) d[i] = 0.f;
                    d = MFMA32(afr[ct1][0], bfr[ctc][0], d);
                    d = MFMA32(afr[ct1][1], bfr[ctc][1], d);
                    d = MFMA32(afr[ct1][2], bfr[ctc][2], d);
                    d = MFMA32(afr[ct1][3], bfr[ctc][3], d);
                    short* mb = MqBt + n * 4096 + (32 * ctc + qc) * 64 + 32 * ct1 + 4 * h;
#pragma unroll
                    for (int rg = 0; rg < 4; ++rg) {
                        bf16x4 ov;
                        ov[0] = f2bf(d[4 * rg + 0]); ov[1] = f2bf(d[4 * rg + 1]);
                        ov[2] = f2bf(d[4 * rg + 2]); ov[3] = f2bf(d[4 * rg + 3]);
                        *(bf16x4*)&mb[8 * rg] = ov;
                    }
                }
        } else if (wv == 1) {
            const int c2 = lane;
            float acc = 0.f;
            for (int a = 0; a < 64; ++a)
                acc += b_q[n * 64 + a] * w_k[(size_t)(n * 64 + a) * 64 + c2];
            row0[n * 64 + c2] = acc * QSCALE;
        } else if (wv == 2) {
            const int c1 = lane;
            float acc = 0.f;
            for (int a = 0; a < 64; ++a)
                acc += b_k[n * 64 + a] * w_q[(size_t)(n * 64 + a) * 64 + c1];
            vn[n * 64 + c1] = acc * QSCALE;
        } else {
            float p = b_q[n * 64 + lane] * b_k[n * 64 + lane];
#pragma unroll
            for (int o = 1; o < 64; o <<= 1) p += __shfl_xor(p, o);
            if (lane == 0) snv[n] = p * QSCALE;
        }
    }
}

// ---------------------------------------------------------------------------
// Kernel 2: fully-fused attention: Q-projection + flash loop + V-projection.
// Block = 512 threads = 8 waves, wave w = head w, ALL waves share one q-tile
// (32 queries) and the SAME K/V LDS staging (heads share K = hidB, V = VtBw).
// grid 256 = 8 b x 32 qt; batch b = XCD (orig&7).
// K-loop: round-12 proven chain (sequenced compute, double-buffer, XOR
// swizzle, distance-1 prefetch); staging split over all 512 threads
// (1 K-chunk + 1 V-chunk each).  Epilogue: normalize, dlayout->B-frags,
// 8 MFMA32 vs wvB, LDS cross-head sum ([i][lane] flat: 2-way conflict,
// free), f32 float4 stores to out.  v_proj kernel + hoB eliminated.
// ---------------------------------------------------------------------------
__global__ __launch_bounds__(512, 1) void attn_fused(
    const short* __restrict__ hidB, const short* __restrict__ VtBw,
    const short* __restrict__ MqBt, const float* __restrict__ row0,
    const float* __restrict__ vn,   const float* __restrict__ snv,
    const float* __restrict__ posRow, const float* __restrict__ posCol,
    const short* __restrict__ wvB, const float* __restrict__ bv,
    float* __restrict__ out)
{
    const int orig = blockIdx.x;           // 0..255
    const int swzb = (orig & 7) * 32 + (orig >> 3);
    const int b    = swzb >> 5;
    const int qt   = swzb & 31;

    const int tid  = threadIdx.x;          // 0..511
    const int w    = tid >> 6;             // wave = head n
    const int n    = w;
    const int lane = tid & 63;
    const int h    = lane >> 5;            // lane half
    const int qc   = lane & 31;            // query column
    const int q    = qt * 32 + qc;
    const int swz  = qc & 7;

    __shared__ __align__(16) short lds[32768];   // 64 KB
    short* const Kst0 = lds;
    short* const Vst0 = lds + 4096;
    short* const Kst1 = lds + 8192;
    short* const Vst1 = lds + 12288;

    // ---- fused Q-side projection (per wave's head) ----
    bf16x8 qf[4];
    float cq;
    {
        const short* hrow = hidB + (((size_t)b * 1024) + q) * 64 + 8 * h;
        bf16x8 hq[4];
#pragma unroll
        for (int kk = 0; kk < 4; ++kk) hq[kk] = *(const bf16x8*)(hrow + 16 * kk);

        float aD[32];
#pragma unroll
        for (int ct = 0; ct < 2; ++ct) {
            f32x16 ci;
            const float* r0p = row0 + n * 64 + 32 * ct + 4 * h;
#pragma unroll
            for (int rg = 0; rg < 4; ++rg) {
                const float4 v = *(const float4*)(r0p + 8 * rg);
                ci[4 * rg + 0] = v.x; ci[4 * rg + 1] = v.y;
                ci[4 * rg + 2] = v.z; ci[4 * rg + 3] = v.w;
            }
            const short* mbase = MqBt + n * 4096 + (size_t)(32 * ct + qc) * 64 + 8 * h;
            ci = MFMA32(*(const bf16x8*)(mbase),      hq[0], ci);
            ci = MFMA32(*(const bf16x8*)(mbase + 16), hq[1], ci);
            ci = MFMA32(*(const bf16x8*)(mbase + 32), hq[2], ci);
            ci = MFMA32(*(const bf16x8*)(mbase + 48), hq[3], ci);
#pragma unroll
            for (int i = 0; i < 16; ++i) aD[16 * ct + i] = ci[i];
        }
        dlayout_to_bfrag(aD, qf);

        float part = 0.f;
#pragma unroll
        for (int kk = 0; kk < 4; ++kk) {
            const float4 v0 = *(const float4*)&vn[n * 64 + 16 * kk + 8 * h];
            const float4 v1 = *(const float4*)&vn[n * 64 + 16 * kk + 8 * h + 4];
            part += bf2f(hq[kk][0]) * v0.x + bf2f(hq[kk][1]) * v0.y +
                    bf2f(hq[kk][2]) * v0.z + bf2f(hq[kk][3]) * v0.w +
                    bf2f(hq[kk][4]) * v1.x + bf2f(hq[kk][5]) * v1.y +
                    bf2f(hq[kk][6]) * v1.z + bf2f(hq[kk][7]) * v1.w;
        }
        cq = xhalf_sum(part) + snv[n];
    }

    // posRow constants + cq fold (kt-invariant)
    float prowA[16];
    {
        const float* pr = posRow + (n * 32 + qc) * 32 + 4 * h;
#pragma unroll
        for (int rg = 0; rg < 4; ++rg) {
            const float4 v = *(const float4*)(pr + 8 * rg);
            prowA[4 * rg + 0] = v.x + cq; prowA[4 * rg + 1] = v.y + cq;
            prowA[4 * rg + 2] = v.z + cq; prowA[4 * rg + 3] = v.w + cq;
        }
    }
    const float* pcp = posCol + (n * 32 + qt) * 32;

    const short* Kbase = hidB + (size_t)b * 65536;          // [s][64] rows = keys
    const short* Vbase = VtBw + (size_t)b * 65536;          // tile-major [kt][d][64]

    // staging: 512 threads, each 1 K-chunk + 1 V-chunk (row = tid>>3, c16 = tid&7)
    const int c16  = tid & 7;
    const int srow = tid >> 3;          // 0..63
    const int woff = srow * 128 + ((c16 ^ (srow & 7)) << 4);
    const short* kp = Kbase + (size_t)srow * 64 + c16 * 8;
    const short* vp = Vbase + (size_t)srow * 64 + c16 * 8;

    float lsum = 0.f;                     // per-half partial (cross-half at end)
    f32x16 oacc[2];
#pragma unroll
    for (int dt = 0; dt < 2; ++dt)
#pragma unroll
        for (int i = 0; i < 16; ++i) oacc[dt][i] = 0.f;

    // compute: sc blocks sequenced (ct0 fully, then ct1) — r14-proven body
    auto compute = [&](int kt, const short* Ktc_s, const short* Vtc_s) {
        const char* Ktc = (const char*)Ktc_s;
        const char* Vtc = (const char*)Vtc_s;
        const float pcv[2] = {pcp[2 * kt], pcp[2 * kt + 1]};

        bf16x8 pfrag[4];
#pragma unroll
        for (int ct = 0; ct < 2; ++ct) {
            bf16x8 kf[4];
            const int rb = (32 * ct + qc) * 128;
#pragma unroll
            for (int k = 0; k < 4; ++k)
                kf[k] = *(const bf16x8*)(Ktc + rb + (((2 * k + h) ^ swz) << 4));

            f32x16 ci;
#pragma unroll
            for (int i = 0; i < 16; ++i) ci[i] = prowA[i] + pcv[ct];
            ci = MFMA32(kf[0], qf[0], ci);
            ci = MFMA32(kf[1], qf[1], ci);
            ci = MFMA32(kf[2], qf[2], ci);
            ci = MFMA32(kf[3], qf[3], ci);

            float p[16];
#pragma unroll
            for (int i = 0; i < 16; ++i) p[i] = __builtin_amdgcn_exp2f(ci[i]);
            float s8[8];
#pragma unroll
            for (int i = 0; i < 8; ++i) s8[i] = p[i] + p[i + 8];
            lsum += ((s8[0] + s8[1]) + (s8[2] + s8[3])) +
                    ((s8[4] + s8[5]) + (s8[6] + s8[7]));
            dhalf_to_bfrag(p, &pfrag[2 * ct]);
        }

        bf16x8 vf[2][4];
#pragma unroll
        for (int dt = 0; dt < 2; ++dt) {
            const int rb = (32 * dt + qc) * 128;
#pragma unroll
            for (int ks = 0; ks < 4; ++ks)
                vf[dt][ks] = *(const bf16x8*)(Vtc + rb + (((2 * ks + h) ^ swz) << 4));
        }
#pragma unroll
        for (int dt = 0; dt < 2; ++dt) {
            f32x16 oa = oacc[dt];
            oa = MFMA32(vf[dt][0], pfrag[0], oa);
            oa = MFMA32(vf[dt][1], pfrag[1], oa);
            oa = MFMA32(vf[dt][2], pfrag[2], oa);
            oacc[dt] = MFMA32(vf[dt][3], pfrag[3], oa);
        }
    };

    // prologue: stage tile 0 into buf0
    {
        const float4 a0 = *(const float4*)kp;
        const float4 a1 = *(const float4*)vp;
        *(float4*)((char*)Kst0 + woff) = a0;
        *(float4*)((char*)Vst0 + woff) = a1;
    }
    __syncthreads();

#pragma unroll 1
    for (int pr = 0; pr < 8; ++pr) {
        const int j0 = 2 * pr, j1 = j0 + 1;
        // iter j0 (buf0): prefetch j0+1, compute, write buf1, barrier
        {
            const size_t o = (size_t)(j0 + 1) * 4096;
            const float4 a0 = *(const float4*)(kp + o);
            const float4 a1 = *(const float4*)(vp + o);
            compute(j0, Kst0, Vst0);
            *(float4*)((char*)Kst1 + woff) = a0;
            *(float4*)((char*)Vst1 + woff) = a1;
            __syncthreads();
        }
        // iter j1 (buf1): prefetch j1+1 unless last, compute, write buf0
        if (j1 < 15) {
            const size_t o = (size_t)(j1 + 1) * 4096;
            const float4 a0 = *(const float4*)(kp + o);
            const float4 a1 = *(const float4*)(vp + o);
            compute(j1, Kst1, Vst1);
            *(float4*)((char*)Kst0 + woff) = a0;
            *(float4*)((char*)Vst0 + woff) = a1;
            __syncthreads();
        } else {
            compute(j1, Kst1, Vst1);
        }
    }

    // ---- fused V-projection ----
    // normalize -> D-layout ho -> B-frags; A = wvB rows (dv); 8 MFMA32.
    const float inv = 1.0f / xhalf_sum(lsum);
    float hoD[32];
#pragma unroll
    for (int dt = 0; dt < 2; ++dt)
#pragma unroll
        for (int i = 0; i < 16; ++i) hoD[16 * dt + i] = oacc[dt][i] * inv;
    bf16x8 hofrag[4];
    dlayout_to_bfrag(hoD, hofrag);

    f32x16 dvacc[2];
#pragma unroll
    for (int ct = 0; ct < 2; ++ct)
#pragma unroll
        for (int i = 0; i < 16; ++i) dvacc[ct][i] = 0.f;
#pragma unroll
    for (int ct = 0; ct < 2; ++ct)
#pragma unroll
        for (int k = 0; k < 4; ++k) {
            const bf16x8 aw = *(const bf16x8*)&wvB[(size_t)(32 * ct + qc) * 512 +
                                                   n * 64 + 16 * k + 8 * h];
            dvacc[ct] = MFMA32(aw, hofrag[k], dvacc[ct]);
        }

    // cross-head sum in LDS: slot n, flat [i][lane] (bank = lane&31: 2-way, free)
    __syncthreads();                       // all waves done with K/V staging LDS
    float* cb = (float*)lds;
#pragma unroll
    for (int i = 0; i < 32; ++i)
        cb[n * 2048 + i * 64 + lane] = dvacc[i >> 4][i & 15];
    __syncthreads();

    // wave w merges reg-indices 4w..4w+3 across all 8 heads, stores f32x4.
    float s[4];
#pragma unroll
    for (int k = 0; k < 4; ++k) {
        const int i = 4 * w + k;
        float acc = 0.f;
#pragma unroll
        for (int nn = 0; nn < 8; ++nn) acc += cb[nn * 2048 + i * 64 + lane];
        s[k] = acc;
    }
    // i = 4w+k -> dv = 32*(w>>2) + 8*(w&3) + 4h + k  (k consecutive)
    const int dvb = 32 * (w >> 2) + 8 * (w & 3) + 4 * h;
    const float4 bb4 = *(const float4*)&bv[dvb];
    const int row = b * 1024 + qt * 32 + qc;
    *(float4*)&out[(size_t)row * 64 + dvb] =
        make_float4(s[0] + bb4.x, s[1] + bb4.y, s[2] + bb4.z, s[3] + bb4.w);
}

// ---------------------------------------------------------------------------
extern "C" void kernel_launch(void* const* d_in, const int* in_sizes, int n_in,
                              void* d_out, int out_size, void* d_ws, size_t ws_size,
                              hipStream_t stream)
{
    const float* hid     = (const float*)d_in[0];
    const float* row_emb = (const float*)d_in[2];
    const float* col_emb = (const float*)d_in[3];
    const float* w_row   = (const float*)d_in[4];
    const float* w_col   = (const float*)d_in[5];
    const float* w_q     = (const float*)d_in[6];
    const float* b_q     = (const float*)d_in[7];
    const float* w_k     = (const float*)d_in[8];
    const float* b_k     = (const float*)d_in[9];
    const float* w_v     = (const float*)d_in[10];
    const float* b_v     = (const float*)d_in[11];
    float* out = (float*)d_out;

    // ws layout:
    // hidB 512K sh | VtB 512K sh | MqBt 32K sh | posRow 8K f32 | posCol 8K f32 |
    // row0 512 f32 | vn 512 f32 | sn 8 f32 | wvB 32K sh
    short* hidB   = (short*)d_ws;
    short* VtBw   = hidB + (size_t)SB * SS * SC;
    short* MqBt   = VtBw + (size_t)SB * SS * SC;
    float* posRow = (float*)(MqBt + SNH * SC * SC);
    float* posCol = posRow + SNH * 32 * 32;
    float* row0   = posCol + SNH * 32 * 32;
    float* vn     = row0 + SNH * SC;
    float* snv    = vn + SNH * SC;
    short* wvB    = (short*)(snv + 8);

    prep1<<<216, 256, 0, stream>>>(row_emb, col_emb, w_row, w_col, w_v, w_q,
                                   w_k, hid, b_q, b_k,
                                   posRow, posCol, wvB, hidB, VtBw,
                                   MqBt, row0, vn, snv);
    attn_fused<<<256, 512, 0, stream>>>(hidB, VtBw, MqBt, row0, vn, snv,
                                        posRow, posCol, wvB, b_v, out);
}

// Round 16
// 39.053 us; speedup vs baseline: 1.4927x; 1.0131x over previous
//
#include <hip/hip_runtime.h>
#include <hip/hip_bf16.h>
#include <cstdint>
#include <cstddef>

// B=8, W=32, H=32, C=64, NH=8, P=64, M=32, AH=512, S=W*H=1024
#define SB 8
#define SNH 8
#define SS 1024
#define SC 64

typedef __attribute__((ext_vector_type(8)))  short bf16x8;
typedef __attribute__((ext_vector_type(4)))  short bf16x4;
typedef __attribute__((ext_vector_type(4)))  float f32x4;
typedef __attribute__((ext_vector_type(16))) float f32x16;
typedef __attribute__((ext_vector_type(4)))  unsigned u32x4;

#define INVLN2 1.44269504088896f
#define QSCALE (0.125f * INVLN2)

static __device__ __forceinline__ short f2bf(float f) {
    __hip_bfloat16 h = __float2bfloat16(f);
    return __builtin_bit_cast(short, h);
}
static __device__ __forceinline__ float bf2f(short s) {
    return __builtin_bit_cast(float, (unsigned)((unsigned short)s) << 16);
}

static __device__ __forceinline__ bf16x8 cvt8(const float* __restrict__ p, float scl) {
    const float4 a = *(const float4*)p;
    const float4 b = *(const float4*)(p + 4);
    bf16x8 o;
    o[0] = f2bf(a.x * scl); o[1] = f2bf(a.y * scl); o[2] = f2bf(a.z * scl); o[3] = f2bf(a.w * scl);
    o[4] = f2bf(b.x * scl); o[5] = f2bf(b.y * scl); o[6] = f2bf(b.z * scl); o[7] = f2bf(b.w * scl);
    return o;
}
static __device__ __forceinline__ bf16x8 cvt8v(float4 a, float4 b) {
    bf16x8 o;
    o[0] = f2bf(a.x); o[1] = f2bf(a.y); o[2] = f2bf(a.z); o[3] = f2bf(a.w);
    o[4] = f2bf(b.x); o[5] = f2bf(b.y); o[6] = f2bf(b.z); o[7] = f2bf(b.w);
    return o;
}

static __device__ __forceinline__ unsigned pk2(float lo, float hi) {
    return (unsigned)(unsigned short)f2bf(lo) | ((unsigned)(unsigned short)f2bf(hi) << 16);
}

#if __has_builtin(__builtin_amdgcn_permlane32_swap)
typedef __attribute__((ext_vector_type(2))) unsigned uint2v;
static __device__ __forceinline__ void plswap(unsigned& a, unsigned& b) {
    uint2v r = __builtin_amdgcn_permlane32_swap(a, b, false, false);
    a = r[0]; b = r[1];
}
#else
static __device__ __forceinline__ void plswap(unsigned& a, unsigned& b) {
    asm volatile("v_permlane32_swap_b32 %0, %1" : "+v"(a), "+v"(b));
}
#endif

static __device__ __forceinline__ float xhalf_sum(float x) {
    unsigned a = __builtin_bit_cast(unsigned, x), b = a;
    plswap(a, b);
    return __builtin_bit_cast(float, a) + __builtin_bit_cast(float, b);
}

#define MFMA32(a, b, c) __builtin_amdgcn_mfma_f32_32x32x16_bf16((a), (b), (c), 0, 0, 0)

// D-layout (32x32) -> B-frag conversion (verified P-path recipe).
static __device__ __forceinline__ void dlayout_to_bfrag(const float* src, bf16x8* dst) {
#pragma unroll
    for (int k = 0; k < 4; ++k) {
        const int base = (k >> 1) * 16 + (k & 1) * 8;
        unsigned w0 = pk2(src[base + 0], src[base + 1]);
        unsigned w2 = pk2(src[base + 4], src[base + 5]);
        plswap(w0, w2);
        unsigned w1 = pk2(src[base + 2], src[base + 3]);
        unsigned w3 = pk2(src[base + 6], src[base + 7]);
        plswap(w1, w3);
        u32x4 uw; uw[0] = w0; uw[1] = w1; uw[2] = w2; uw[3] = w3;
        dst[k] = __builtin_bit_cast(bf16x8, uw);
    }
}

// half-of-D-layout (16 values, one sc block) -> 2 B-frags
static __device__ __forceinline__ void dhalf_to_bfrag(const float* src, bf16x8* dst) {
#pragma unroll
    for (int k = 0; k < 2; ++k) {
        const int base = k * 8;
        unsigned w0 = pk2(src[base + 0], src[base + 1]);
        unsigned w2 = pk2(src[base + 4], src[base + 5]);
        plswap(w0, w2);
        unsigned w1 = pk2(src[base + 2], src[base + 3]);
        unsigned w3 = pk2(src[base + 6], src[base + 7]);
        plswap(w1, w3);
        u32x4 uw; uw[0] = w0; uw[1] = w1; uw[2] = w2; uw[3] = w3;
        dst[k] = __builtin_bit_cast(bf16x8, uw);
    }
}

// ---------------------------------------------------------------------------
// Kernel 1: prep1 — pos tables, wv->bf16, hid->hidB + V^T (one hid pass),
// and per-head composite matrices M_n = QSCALE*wq_n^T wk_n (+ bias vectors).
// blocks: [0,64) pos | [64,80) wvB | [80,208) hidB+VtB | [208,216) M_n.
// ---------------------------------------------------------------------------
__global__ __launch_bounds__(256) void prep1(
    const float* __restrict__ row_emb, const float* __restrict__ col_emb,
    const float* __restrict__ w_row,   const float* __restrict__ w_col,
    const float* __restrict__ w_v,  const float* __restrict__ w_q,
    const float* __restrict__ w_k,  const float* __restrict__ hid,
    const float* __restrict__ b_q,  const float* __restrict__ b_k,
    float* __restrict__ posRow, float* __restrict__ posCol,
    short* __restrict__ wvB, short* __restrict__ hidB, short* __restrict__ VtBw,
    short* __restrict__ MqBt, float* __restrict__ row0,
    float* __restrict__ vn, float* __restrict__ snv)
{
    const int bx = blockIdx.x;
    const int tid = threadIdx.x;
    __shared__ float T[64][65];

    if (bx < 64) {
        const int idx = bx * 256 + tid;     // 0..16383
        const int which = idx >> 13;
        const int r = idx & 8191;
        const int n = r >> 10;
        const int j = (r >> 5) & 31;
        const int l = r & 31;
        const float* emb = which ? col_emb : row_emb;
        const float* wgt = which ? w_col : w_row;
        const int e = l - j + 31;
        float acc = 0.f;
        for (int p = 0; p < 64; p += 4) {
            const float4 ev = *(const float4*)&emb[e * 64 + p];
            const float4 wv4 = *(const float4*)&wgt[n * 64 + p];
            acc += ev.x * wv4.x + ev.y * wv4.y + ev.z * wv4.z + ev.w * wv4.w;
        }
        (which ? posCol : posRow)[r] = acc * INVLN2;
    } else if (bx < 80) {
        const int t = (bx - 64) * 256 + tid;          // 0..4095
        *(bf16x8*)&wvB[t * 8] = cvt8(&w_v[t * 8], 1.0f);
    } else if (bx < 208) {
        // hid tile -> hidB (straight bf16) + VtBw (tile-major transpose)
        const int z = bx - 80;              // 0..127, batch b on XCD b (z&7)
        const int b = z & 7, kt = z >> 3;
        const int r  = tid >> 2;            // 0..63
        const int c0 = (tid & 3) * 16;
        const float* src = hid + (((size_t)b * 1024) + kt * 64 + r) * 64 + c0;
        const float4 f0 = ((const float4*)src)[0];
        const float4 f1 = ((const float4*)src)[1];
        const float4 f2 = ((const float4*)src)[2];
        const float4 f3 = ((const float4*)src)[3];
        T[r][c0 + 0] = f0.x; T[r][c0 + 1] = f0.y; T[r][c0 + 2] = f0.z; T[r][c0 + 3] = f0.w;
        T[r][c0 + 4] = f1.x; T[r][c0 + 5] = f1.y; T[r][c0 + 6] = f1.z; T[r][c0 + 7] = f1.w;
        T[r][c0 + 8] = f2.x; T[r][c0 + 9] = f2.y; T[r][c0 +10] = f2.z; T[r][c0 +11] = f2.w;
        T[r][c0 +12] = f3.x; T[r][c0 +13] = f3.y; T[r][c0 +14] = f3.z; T[r][c0 +15] = f3.w;
        short* hb = hidB + (((size_t)b * 1024) + kt * 64 + r) * 64 + c0;
        *(bf16x8*)(hb)     = cvt8v(f0, f1);
        *(bf16x8*)(hb + 8) = cvt8v(f2, f3);
        __syncthreads();
        short* tbase = VtBw + ((size_t)(b * 16 + kt)) * 4096;
#pragma unroll
        for (int it = 0; it < 2; ++it) {
            const int d  = (tid >> 3) + 32 * it;
            const int k0 = (tid & 7) * 8;
            bf16x8 o;
#pragma unroll
            for (int j = 0; j < 8; ++j) o[j] = f2bf(T[k0 + j][d]);
            *(bf16x8*)&tbase[d * 64 + k0] = o;
        }
    } else {
        // per-head composite: M_n, row0_n = bq@wk_n, vn = bk@wq_n, sn = bq.bk
        const int n = bx - 208;             // 0..7
        const int wv = tid >> 6;
        const int lane = tid & 63;
        if (wv == 0) {
            const int h = lane >> 5, qc = lane & 31;
            bf16x8 afr[2][4], bfr[2][4];
#pragma unroll
            for (int ct = 0; ct < 2; ++ct)
#pragma unroll
                for (int k = 0; k < 4; ++k) {
                    bf16x8 oa, ob;
#pragma unroll
                    for (int j = 0; j < 8; ++j) {
                        const int a = 16 * k + 8 * h + j;
                        oa[j] = f2bf(w_q[(size_t)(n * 64 + a) * 64 + 32 * ct + qc] * QSCALE);
                        ob[j] = f2bf(w_k[(size_t)(n * 64 + a) * 64 + 32 * ct + qc]);
                    }
                    afr[ct][k] = oa; bfr[ct][k] = ob;
                }
#pragma unroll
            for (int ct1 = 0; ct1 < 2; ++ct1)
#pragma unroll
                for (int ctc = 0; ctc < 2; ++ctc) {
                    f32x16 d;
#pragma unroll
                    for (int i = 0; i < 16; ++i) d[i] = 0.f;
                    d = MFMA32(afr[ct1][0], bfr[ctc][0], d);
                    d = MFMA32(afr[ct1][1], bfr[ctc][1], d);
                    d = MFMA32(afr[ct1][2], bfr[ctc][2], d);
                    d = MFMA32(afr[ct1][3], bfr[ctc][3], d);
                    short* mb = MqBt + n * 4096 + (32 * ctc + qc) * 64 + 32 * ct1 + 4 * h;
#pragma unroll
                    for (int rg = 0; rg < 4; ++rg) {
                        bf16x4 ov;
                        ov[0] = f2bf(d[4 * rg + 0]); ov[1] = f2bf(d[4 * rg + 1]);
                        ov[2] = f2bf(d[4 * rg + 2]); ov[3] = f2bf(d[4 * rg + 3]);
                        *(bf16x4*)&mb[8 * rg] = ov;
                    }
                }
        } else if (wv == 1) {
            const int c2 = lane;
            float acc = 0.f;
            for (int a = 0; a < 64; ++a)
                acc += b_q[n * 64 + a] * w_k[(size_t)(n * 64 + a) * 64 + c2];
            row0[n * 64 + c2] = acc * QSCALE;
        } else if (wv == 2) {
            const int c1 = lane;
            float acc = 0.f;
            for (int a = 0; a < 64; ++a)
                acc += b_k[n * 64 + a] * w_q[(size_t)(n * 64 + a) * 64 + c1];
            vn[n * 64 + c1] = acc * QSCALE;
        } else {
            float p = b_q[n * 64 + lane] * b_k[n * 64 + lane];
#pragma unroll
            for (int o = 1; o < 64; o <<= 1) p += __shfl_xor(p, o);
            if (lane == 0) snv[n] = p * QSCALE;
        }
    }
}

// ---------------------------------------------------------------------------
// Kernel 2: fully-fused attention: Q-projection + flash loop + V-projection.
// Block = 512 threads = 8 waves, wave w = head w, all waves share one q-tile
// and the SAME K/V LDS staging.  grid 256 = 1 block/CU -> VGPR cap is 256,
// so a 2-compute barrier window is register-feasible (r13's spill was at the
// 128 cap with the fat body).  4 buffer pairs (64 KB, reused by combine);
// ONE barrier per 2 tiles (8 barriers vs 16); two sequenced compute chains
// per window give cross-tile ILP.  batch b = XCD (orig&7).
// ---------------------------------------------------------------------------
__global__ __launch_bounds__(512, 1) void attn_fused(
    const short* __restrict__ hidB, const short* __restrict__ VtBw,
    const short* __restrict__ MqBt, const float* __restrict__ row0,
    const float* __restrict__ vn,   const float* __restrict__ snv,
    const float* __restrict__ posRow, const float* __restrict__ posCol,
    const short* __restrict__ wvB, const float* __restrict__ bv,
    float* __restrict__ out)
{
    const int orig = blockIdx.x;           // 0..255
    const int swzb = (orig & 7) * 32 + (orig >> 3);
    const int b    = swzb >> 5;
    const int qt   = swzb & 31;

    const int tid  = threadIdx.x;          // 0..511
    const int w    = tid >> 6;             // wave = head n
    const int n    = w;
    const int lane = tid & 63;
    const int h    = lane >> 5;            // lane half
    const int qc   = lane & 31;            // query column
    const int q    = qt * 32 + qc;
    const int swz  = qc & 7;

    __shared__ __align__(16) short lds[32768];   // 64 KB
    short* const Kst0 = lds;
    short* const Vst0 = lds + 4096;
    short* const Kst1 = lds + 8192;
    short* const Vst1 = lds + 12288;
    short* const Kst2 = lds + 16384;
    short* const Vst2 = lds + 20480;
    short* const Kst3 = lds + 24576;
    short* const Vst3 = lds + 28672;

    // ---- fused Q-side projection (per wave's head) ----
    bf16x8 qf[4];
    float cq;
    {
        const short* hrow = hidB + (((size_t)b * 1024) + q) * 64 + 8 * h;
        bf16x8 hq[4];
#pragma unroll
        for (int kk = 0; kk < 4; ++kk) hq[kk] = *(const bf16x8*)(hrow + 16 * kk);

        float aD[32];
#pragma unroll
        for (int ct = 0; ct < 2; ++ct) {
            f32x16 ci;
            const float* r0p = row0 + n * 64 + 32 * ct + 4 * h;
#pragma unroll
            for (int rg = 0; rg < 4; ++rg) {
                const float4 v = *(const float4*)(r0p + 8 * rg);
                ci[4 * rg + 0] = v.x; ci[4 * rg + 1] = v.y;
                ci[4 * rg + 2] = v.z; ci[4 * rg + 3] = v.w;
            }
            const short* mbase = MqBt + n * 4096 + (size_t)(32 * ct + qc) * 64 + 8 * h;
            ci = MFMA32(*(const bf16x8*)(mbase),      hq[0], ci);
            ci = MFMA32(*(const bf16x8*)(mbase + 16), hq[1], ci);
            ci = MFMA32(*(const bf16x8*)(mbase + 32), hq[2], ci);
            ci = MFMA32(*(const bf16x8*)(mbase + 48), hq[3], ci);
#pragma unroll
            for (int i = 0; i < 16; ++i) aD[16 * ct + i] = ci[i];
        }
        dlayout_to_bfrag(aD, qf);

        float part = 0.f;
#pragma unroll
        for (int kk = 0; kk < 4; ++kk) {
            const float4 v0 = *(const float4*)&vn[n * 64 + 16 * kk + 8 * h];
            const float4 v1 = *(const float4*)&vn[n * 64 + 16 * kk + 8 * h + 4];
            part += bf2f(hq[kk][0]) * v0.x + bf2f(hq[kk][1]) * v0.y +
                    bf2f(hq[kk][2]) * v0.z + bf2f(hq[kk][3]) * v0.w +
                    bf2f(hq[kk][4]) * v1.x + bf2f(hq[kk][5]) * v1.y +
                    bf2f(hq[kk][6]) * v1.z + bf2f(hq[kk][7]) * v1.w;
        }
        cq = xhalf_sum(part) + snv[n];
    }

    // posRow constants + cq fold (kt-invariant)
    float prowA[16];
    {
        const float* pr = posRow + (n * 32 + qc) * 32 + 4 * h;
#pragma unroll
        for (int rg = 0; rg < 4; ++rg) {
            const float4 v = *(const float4*)(pr + 8 * rg);
            prowA[4 * rg + 0] = v.x + cq; prowA[4 * rg + 1] = v.y + cq;
            prowA[4 * rg + 2] = v.z + cq; prowA[4 * rg + 3] = v.w + cq;
        }
    }
    const float* pcp = posCol + (n * 32 + qt) * 32;

    const short* Kbase = hidB + (size_t)b * 65536;          // [s][64] rows = keys
    const short* Vbase = VtBw + (size_t)b * 65536;          // tile-major [kt][d][64]

    // staging: 512 threads, each 1 K-chunk + 1 V-chunk (row = tid>>3, c16 = tid&7)
    const int c16  = tid & 7;
    const int srow = tid >> 3;          // 0..63
    const int woff = srow * 128 + ((c16 ^ (srow & 7)) << 4);
    const short* kp = Kbase + (size_t)srow * 64 + c16 * 8;
    const short* vp = Vbase + (size_t)srow * 64 + c16 * 8;

    float lsum = 0.f;                     // per-half partial (cross-half at end)
    f32x16 oacc[2];
#pragma unroll
    for (int dt = 0; dt < 2; ++dt)
#pragma unroll
        for (int i = 0; i < 16; ++i) oacc[dt][i] = 0.f;

    // compute: sc blocks sequenced (ct0 fully, then ct1) — r14-proven body
    auto compute = [&](int kt, const short* Ktc_s, const short* Vtc_s) {
        const char* Ktc = (const char*)Ktc_s;
        const char* Vtc = (const char*)Vtc_s;
        const float pcv[2] = {pcp[2 * kt], pcp[2 * kt + 1]};

        bf16x8 pfrag[4];
#pragma unroll
        for (int ct = 0; ct < 2; ++ct) {
            bf16x8 kf[4];
            const int rb = (32 * ct + qc) * 128;
#pragma unroll
            for (int k = 0; k < 4; ++k)
                kf[k] = *(const bf16x8*)(Ktc + rb + (((2 * k + h) ^ swz) << 4));

            f32x16 ci;
#pragma unroll
            for (int i = 0; i < 16; ++i) ci[i] = prowA[i] + pcv[ct];
            ci = MFMA32(kf[0], qf[0], ci);
            ci = MFMA32(kf[1], qf[1], ci);
            ci = MFMA32(kf[2], qf[2], ci);
            ci = MFMA32(kf[3], qf[3], ci);

            float p[16];
#pragma unroll
            for (int i = 0; i < 16; ++i) p[i] = __builtin_amdgcn_exp2f(ci[i]);
            float s8[8];
#pragma unroll
            for (int i = 0; i < 8; ++i) s8[i] = p[i] + p[i + 8];
            lsum += ((s8[0] + s8[1]) + (s8[2] + s8[3])) +
                    ((s8[4] + s8[5]) + (s8[6] + s8[7]));
            dhalf_to_bfrag(p, &pfrag[2 * ct]);
        }

        bf16x8 vf[2][4];
#pragma unroll
        for (int dt = 0; dt < 2; ++dt) {
            const int rb = (32 * dt + qc) * 128;
#pragma unroll
            for (int ks = 0; ks < 4; ++ks)
                vf[dt][ks] = *(const bf16x8*)(Vtc + rb + (((2 * ks + h) ^ swz) << 4));
        }
#pragma unroll
        for (int dt = 0; dt < 2; ++dt) {
            f32x16 oa = oacc[dt];
            oa = MFMA32(vf[dt][0], pfrag[0], oa);
            oa = MFMA32(vf[dt][1], pfrag[1], oa);
            oa = MFMA32(vf[dt][2], pfrag[2], oa);
            oacc[dt] = MFMA32(vf[dt][3], pfrag[3], oa);
        }
    };

    // prologue: stage tiles 0,1 into pair0
    {
        const float4 a0 = *(const float4*)kp;
        const float4 a1 = *(const float4*)vp;
        const float4 b0 = *(const float4*)(kp + 4096);
        const float4 b1 = *(const float4*)(vp + 4096);
        *(float4*)((char*)Kst0 + woff) = a0;
        *(float4*)((char*)Vst0 + woff) = a1;
        *(float4*)((char*)Kst1 + woff) = b0;
        *(float4*)((char*)Vst1 + woff) = b1;
    }
    __syncthreads();

    // main loop: 4 super-iters, 2 windows each; window = 2 tiles, 1 barrier
#pragma unroll 1
    for (int i = 0; i < 4; ++i) {
        const int t0 = 4 * i;
        // window A (pair0): compute t0, t0+1; stage t0+2, t0+3 -> pair1
        {
            const size_t oA = (size_t)(t0 + 2) * 4096;
            const size_t oB = (size_t)(t0 + 3) * 4096;
            const float4 ka2 = *(const float4*)(kp + oA);
            const float4 va2 = *(const float4*)(vp + oA);
            const float4 ka3 = *(const float4*)(kp + oB);
            const float4 va3 = *(const float4*)(vp + oB);
            compute(t0,     Kst0, Vst0);
            compute(t0 + 1, Kst1, Vst1);
            *(float4*)((char*)Kst2 + woff) = ka2;
            *(float4*)((char*)Vst2 + woff) = va2;
            *(float4*)((char*)Kst3 + woff) = ka3;
            *(float4*)((char*)Vst3 + woff) = va3;
            __syncthreads();
        }
        // window B (pair1): compute t0+2, t0+3; stage t0+4, t0+5 -> pair0
        if (i < 3) {
            const size_t oA = (size_t)(t0 + 4) * 4096;
            const size_t oB = (size_t)(t0 + 5) * 4096;
            const float4 ka4 = *(const float4*)(kp + oA);
            const float4 va4 = *(const float4*)(vp + oA);
            const float4 ka5 = *(const float4*)(kp + oB);
            const float4 va5 = *(const float4*)(vp + oB);
            compute(t0 + 2, Kst2, Vst2);
            compute(t0 + 3, Kst3, Vst3);
            *(float4*)((char*)Kst0 + woff) = ka4;
            *(float4*)((char*)Vst0 + woff) = va4;
            *(float4*)((char*)Kst1 + woff) = ka5;
            *(float4*)((char*)Vst1 + woff) = va5;
            __syncthreads();
        } else {
            compute(14, Kst2, Vst2);
            compute(15, Kst3, Vst3);
        }
    }

    // ---- fused V-projection ----
    const float inv = 1.0f / xhalf_sum(lsum);
    float hoD[32];
#pragma unroll
    for (int dt = 0; dt < 2; ++dt)
#pragma unroll
        for (int i = 0; i < 16; ++i) hoD[16 * dt + i] = oacc[dt][i] * inv;
    bf16x8 hofrag[4];
    dlayout_to_bfrag(hoD, hofrag);

    f32x16 dvacc[2];
#pragma unroll
    for (int ct = 0; ct < 2; ++ct)
#pragma unroll
        for (int i = 0; i < 16; ++i) dvacc[ct][i] = 0.f;
#pragma unroll
    for (int ct = 0; ct < 2; ++ct)
#pragma unroll
        for (int k = 0; k < 4; ++k) {
            const bf16x8 aw = *(const bf16x8*)&wvB[(size_t)(32 * ct + qc) * 512 +
                                                   n * 64 + 16 * k + 8 * h];
            dvacc[ct] = MFMA32(aw, hofrag[k], dvacc[ct]);
        }

    // cross-head sum in LDS: slot n, flat [i][lane] (bank = lane&31: 2-way, free)
    __syncthreads();                       // all waves done with K/V staging LDS
    float* cb = (float*)lds;
#pragma unroll
    for (int i = 0; i < 32; ++i)
        cb[n * 2048 + i * 64 + lane] = dvacc[i >> 4][i & 15];
    __syncthreads();

    // wave w merges reg-indices 4w..4w+3 across all 8 heads, stores f32x4.
    float s[4];
#pragma unroll
    for (int k = 0; k < 4; ++k) {
        const int i = 4 * w + k;
        float acc = 0.f;
#pragma unroll
        for (int nn = 0; nn < 8; ++nn) acc += cb[nn * 2048 + i * 64 + lane];
        s[k] = acc;
    }
    // i = 4w+k -> dv = 32*(w>>2) + 8*(w&3) + 4h + k  (k consecutive)
    const int dvb = 32 * (w >> 2) + 8 * (w & 3) + 4 * h;
    const float4 bb4 = *(const float4*)&bv[dvb];
    const int row = b * 1024 + qt * 32 + qc;
    *(float4*)&out[(size_t)row * 64 + dvb] =
        make_float4(s[0] + bb4.x, s[1] + bb4.y, s[2] + bb4.z, s[3] + bb4.w);
}

// ---------------------------------------------------------------------------
extern "C" void kernel_launch(void* const* d_in, const int* in_sizes, int n_in,
                              void* d_out, int out_size, void* d_ws, size_t ws_size,
                              hipStream_t stream)
{
    const float* hid     = (const float*)d_in[0];
    const float* row_emb = (const float*)d_in[2];
    const float* col_emb = (const float*)d_in[3];
    const float* w_row   = (const float*)d_in[4];
    const float* w_col   = (const float*)d_in[5];
    const float* w_q     = (const float*)d_in[6];
    const float* b_q     = (const float*)d_in[7];
    const float* w_k     = (const float*)d_in[8];
    const float* b_k     = (const float*)d_in[9];
    const float* w_v     = (const float*)d_in[10];
    const float* b_v     = (const float*)d_in[11];
    float* out = (float*)d_out;

    // ws layout:
    // hidB 512K sh | VtB 512K sh | MqBt 32K sh | posRow 8K f32 | posCol 8K f32 |
    // row0 512 f32 | vn 512 f32 | sn 8 f32 | wvB 32K sh
    short* hidB   = (short*)d_ws;
    short* VtBw   = hidB + (size_t)SB * SS * SC;
    short* MqBt   = VtBw + (size_t)SB * SS * SC;
    float* posRow = (float*)(MqBt + SNH * SC * SC);
    float* posCol = posRow + SNH * 32 * 32;
    float* row0   = posCol + SNH * 32 * 32;
    float* vn     = row0 + SNH * SC;
    float* snv    = vn + SNH * SC;
    short* wvB    = (short*)(snv + 8);

    prep1<<<216, 256, 0, stream>>>(row_emb, col_emb, w_row, w_col, w_v, w_q,
                                   w_k, hid, b_q, b_k,
                                   posRow, posCol, wvB, hidB, VtBw,
                                   MqBt, row0, vn, snv);
    attn_fused<<<256, 512, 0, stream>>>(hidB, VtBw, MqBt, row0, vn, snv,
                                        posRow, posCol, wvB, b_v, out);
}

// Round 17
// 38.961 us; speedup vs baseline: 1.4962x; 1.0024x over previous
//
#include <hip/hip_runtime.h>
#include <hip/hip_bf16.h>
#include <cstdint>
#include <cstddef>

// B=8, W=32, H=32, C=64, NH=8, P=64, M=32, AH=512, S=W*H=1024
#define SB 8
#define SNH 8
#define SS 1024
#define SC 64

typedef __attribute__((ext_vector_type(8)))  short bf16x8;
typedef __attribute__((ext_vector_type(4)))  short bf16x4;
typedef __attribute__((ext_vector_type(4)))  float f32x4;
typedef __attribute__((ext_vector_type(16))) float f32x16;
typedef __attribute__((ext_vector_type(4)))  unsigned u32x4;

#define INVLN2 1.44269504088896f
#define QSCALE (0.125f * INVLN2)

static __device__ __forceinline__ short f2bf(float f) {
    __hip_bfloat16 h = __float2bfloat16(f);
    return __builtin_bit_cast(short, h);
}
static __device__ __forceinline__ float bf2f(short s) {
    return __builtin_bit_cast(float, (unsigned)((unsigned short)s) << 16);
}

static __device__ __forceinline__ bf16x8 cvt8(const float* __restrict__ p, float scl) {
    const float4 a = *(const float4*)p;
    const float4 b = *(const float4*)(p + 4);
    bf16x8 o;
    o[0] = f2bf(a.x * scl); o[1] = f2bf(a.y * scl); o[2] = f2bf(a.z * scl); o[3] = f2bf(a.w * scl);
    o[4] = f2bf(b.x * scl); o[5] = f2bf(b.y * scl); o[6] = f2bf(b.z * scl); o[7] = f2bf(b.w * scl);
    return o;
}
static __device__ __forceinline__ bf16x8 cvt8v(float4 a, float4 b) {
    bf16x8 o;
    o[0] = f2bf(a.x); o[1] = f2bf(a.y); o[2] = f2bf(a.z); o[3] = f2bf(a.w);
    o[4] = f2bf(b.x); o[5] = f2bf(b.y); o[6] = f2bf(b.z); o[7] = f2bf(b.w);
    return o;
}

static __device__ __forceinline__ unsigned pk2(float lo, float hi) {
    return (unsigned)(unsigned short)f2bf(lo) | ((unsigned)(unsigned short)f2bf(hi) << 16);
}

#if __has_builtin(__builtin_amdgcn_permlane32_swap)
typedef __attribute__((ext_vector_type(2))) unsigned uint2v;
static __device__ __forceinline__ void plswap(unsigned& a, unsigned& b) {
    uint2v r = __builtin_amdgcn_permlane32_swap(a, b, false, false);
    a = r[0]; b = r[1];
}
#else
static __device__ __forceinline__ void plswap(unsigned& a, unsigned& b) {
    asm volatile("v_permlane32_swap_b32 %0, %1" : "+v"(a), "+v"(b));
}
#endif

static __device__ __forceinline__ float xhalf_sum(float x) {
    unsigned a = __builtin_bit_cast(unsigned, x), b = a;
    plswap(a, b);
    return __builtin_bit_cast(float, a) + __builtin_bit_cast(float, b);
}

#define MFMA32(a, b, c) __builtin_amdgcn_mfma_f32_32x32x16_bf16((a), (b), (c), 0, 0, 0)

// D-layout (32x32) -> B-frag conversion (verified P-path recipe).
static __device__ __forceinline__ void dlayout_to_bfrag(const float* src, bf16x8* dst) {
#pragma unroll
    for (int k = 0; k < 4; ++k) {
        const int base = (k >> 1) * 16 + (k & 1) * 8;
        unsigned w0 = pk2(src[base + 0], src[base + 1]);
        unsigned w2 = pk2(src[base + 4], src[base + 5]);
        plswap(w0, w2);
        unsigned w1 = pk2(src[base + 2], src[base + 3]);
        unsigned w3 = pk2(src[base + 6], src[base + 7]);
        plswap(w1, w3);
        u32x4 uw; uw[0] = w0; uw[1] = w1; uw[2] = w2; uw[3] = w3;
        dst[k] = __builtin_bit_cast(bf16x8, uw);
    }
}

// half-of-D-layout (16 values, one sc block) -> 2 B-frags
static __device__ __forceinline__ void dhalf_to_bfrag(const float* src, bf16x8* dst) {
#pragma unroll
    for (int k = 0; k < 2; ++k) {
        const int base = k * 8;
        unsigned w0 = pk2(src[base + 0], src[base + 1]);
        unsigned w2 = pk2(src[base + 4], src[base + 5]);
        plswap(w0, w2);
        unsigned w1 = pk2(src[base + 2], src[base + 3]);
        unsigned w3 = pk2(src[base + 6], src[base + 7]);
        plswap(w1, w3);
        u32x4 uw; uw[0] = w0; uw[1] = w1; uw[2] = w2; uw[3] = w3;
        dst[k] = __builtin_bit_cast(bf16x8, uw);
    }
}

// ---------------------------------------------------------------------------
// Kernel 1: prep1 — pos tables, wv->bf16, hid->hidB + V^T (one hid pass),
// and per-head composite matrices M_n = QSCALE*wq_n^T wk_n (+ bias vectors).
// blocks: [0,64) pos | [64,80) wvB | [80,208) hidB+VtB | [208,216) M_n.
// ---------------------------------------------------------------------------
__global__ __launch_bounds__(256) void prep1(
    const float* __restrict__ row_emb, const float* __restrict__ col_emb,
    const float* __restrict__ w_row,   const float* __restrict__ w_col,
    const float* __restrict__ w_v,  const float* __restrict__ w_q,
    const float* __restrict__ w_k,  const float* __restrict__ hid,
    const float* __restrict__ b_q,  const float* __restrict__ b_k,
    float* __restrict__ posRow, float* __restrict__ posCol,
    short* __restrict__ wvB, short* __restrict__ hidB, short* __restrict__ VtBw,
    short* __restrict__ MqBt, float* __restrict__ row0,
    float* __restrict__ vn, float* __restrict__ snv)
{
    const int bx = blockIdx.x;
    const int tid = threadIdx.x;
    __shared__ float T[64][65];

    if (bx < 64) {
        const int idx = bx * 256 + tid;     // 0..16383
        const int which = idx >> 13;
        const int r = idx & 8191;
        const int n = r >> 10;
        const int j = (r >> 5) & 31;
        const int l = r & 31;
        const float* emb = which ? col_emb : row_emb;
        const float* wgt = which ? w_col : w_row;
        const int e = l - j + 31;
        float acc = 0.f;
        for (int p = 0; p < 64; p += 4) {
            const float4 ev = *(const float4*)&emb[e * 64 + p];
            const float4 wv4 = *(const float4*)&wgt[n * 64 + p];
            acc += ev.x * wv4.x + ev.y * wv4.y + ev.z * wv4.z + ev.w * wv4.w;
        }
        (which ? posCol : posRow)[r] = acc * INVLN2;
    } else if (bx < 80) {
        const int t = (bx - 64) * 256 + tid;          // 0..4095
        *(bf16x8*)&wvB[t * 8] = cvt8(&w_v[t * 8], 1.0f);
    } else if (bx < 208) {
        // hid tile -> hidB (straight bf16) + VtBw (tile-major transpose)
        const int z = bx - 80;              // 0..127, batch b on XCD b (z&7)
        const int b = z & 7, kt = z >> 3;
        const int r  = tid >> 2;            // 0..63
        const int c0 = (tid & 3) * 16;
        const float* src = hid + (((size_t)b * 1024) + kt * 64 + r) * 64 + c0;
        const float4 f0 = ((const float4*)src)[0];
        const float4 f1 = ((const float4*)src)[1];
        const float4 f2 = ((const float4*)src)[2];
        const float4 f3 = ((const float4*)src)[3];
        T[r][c0 + 0] = f0.x; T[r][c0 + 1] = f0.y; T[r][c0 + 2] = f0.z; T[r][c0 + 3] = f0.w;
        T[r][c0 + 4] = f1.x; T[r][c0 + 5] = f1.y; T[r][c0 + 6] = f1.z; T[r][c0 + 7] = f1.w;
        T[r][c0 + 8] = f2.x; T[r][c0 + 9] = f2.y; T[r][c0 +10] = f2.z; T[r][c0 +11] = f2.w;
        T[r][c0 +12] = f3.x; T[r][c0 +13] = f3.y; T[r][c0 +14] = f3.z; T[r][c0 +15] = f3.w;
        short* hb = hidB + (((size_t)b * 1024) + kt * 64 + r) * 64 + c0;
        *(bf16x8*)(hb)     = cvt8v(f0, f1);
        *(bf16x8*)(hb + 8) = cvt8v(f2, f3);
        __syncthreads();
        short* tbase = VtBw + ((size_t)(b * 16 + kt)) * 4096;
#pragma unroll
        for (int it = 0; it < 2; ++it) {
            const int d  = (tid >> 3) + 32 * it;
            const int k0 = (tid & 7) * 8;
            bf16x8 o;
#pragma unroll
            for (int j = 0; j < 8; ++j) o[j] = f2bf(T[k0 + j][d]);
            *(bf16x8*)&tbase[d * 64 + k0] = o;
        }
    } else {
        // per-head composite: M_n, row0_n = bq@wk_n, vn = bk@wq_n, sn = bq.bk
        const int n = bx - 208;             // 0..7
        const int wv = tid >> 6;
        const int lane = tid & 63;
        if (wv == 0) {
            const int h = lane >> 5, qc = lane & 31;
            bf16x8 afr[2][4], bfr[2][4];
#pragma unroll
            for (int ct = 0; ct < 2; ++ct)
#pragma unroll
                for (int k = 0; k < 4; ++k) {
                    bf16x8 oa, ob;
#pragma unroll
                    for (int j = 0; j < 8; ++j) {
                        const int a = 16 * k + 8 * h + j;
                        oa[j] = f2bf(w_q[(size_t)(n * 64 + a) * 64 + 32 * ct + qc] * QSCALE);
                        ob[j] = f2bf(w_k[(size_t)(n * 64 + a) * 64 + 32 * ct + qc]);
                    }
                    afr[ct][k] = oa; bfr[ct][k] = ob;
                }
#pragma unroll
            for (int ct1 = 0; ct1 < 2; ++ct1)
#pragma unroll
                for (int ctc = 0; ctc < 2; ++ctc) {
                    f32x16 d;
#pragma unroll
                    for (int i = 0; i < 16; ++i) d[i] = 0.f;
                    d = MFMA32(afr[ct1][0], bfr[ctc][0], d);
                    d = MFMA32(afr[ct1][1], bfr[ctc][1], d);
                    d = MFMA32(afr[ct1][2], bfr[ctc][2], d);
                    d = MFMA32(afr[ct1][3], bfr[ctc][3], d);
                    short* mb = MqBt + n * 4096 + (32 * ctc + qc) * 64 + 32 * ct1 + 4 * h;
#pragma unroll
                    for (int rg = 0; rg < 4; ++rg) {
                        bf16x4 ov;
                        ov[0] = f2bf(d[4 * rg + 0]); ov[1] = f2bf(d[4 * rg + 1]);
                        ov[2] = f2bf(d[4 * rg + 2]); ov[3] = f2bf(d[4 * rg + 3]);
                        *(bf16x4*)&mb[8 * rg] = ov;
                    }
                }
        } else if (wv == 1) {
            const int c2 = lane;
            float acc = 0.f;
            for (int a = 0; a < 64; ++a)
                acc += b_q[n * 64 + a] * w_k[(size_t)(n * 64 + a) * 64 + c2];
            row0[n * 64 + c2] = acc * QSCALE;
        } else if (wv == 2) {
            const int c1 = lane;
            float acc = 0.f;
            for (int a = 0; a < 64; ++a)
                acc += b_k[n * 64 + a] * w_q[(size_t)(n * 64 + a) * 64 + c1];
            vn[n * 64 + c1] = acc * QSCALE;
        } else {
            float p = b_q[n * 64 + lane] * b_k[n * 64 + lane];
#pragma unroll
            for (int o = 1; o < 64; o <<= 1) p += __shfl_xor(p, o);
            if (lane == 0) snv[n] = p * QSCALE;
        }
    }
}

// ---------------------------------------------------------------------------
// Kernel 2: fully-fused attention: Q-projection + flash loop + V-projection.
// Block = 512 threads = 8 waves, wave w = head w, all waves share one q-tile
// and the SAME K/V LDS staging.  grid 256 = 1 block/CU (VGPR cap 256).
// Window = 2 tiles, phases split: qk(t0); vf(t0); qk(t1); vf(t1);
// smpv(t0); smpv(t1) — all LDS reads issue early, tile-1's QK MFMAs are
// independent of tile-0's softmax so the scheduler interleaves the MFMA
// pipe under the trans/VALU phases (cross-tile ILP, register-feasible at
// 1 block/CU; r13's spill was at the 128 cap).  batch b = XCD (orig&7).
// ---------------------------------------------------------------------------
__global__ __launch_bounds__(512, 1) void attn_fused(
    const short* __restrict__ hidB, const short* __restrict__ VtBw,
    const short* __restrict__ MqBt, const float* __restrict__ row0,
    const float* __restrict__ vn,   const float* __restrict__ snv,
    const float* __restrict__ posRow, const float* __restrict__ posCol,
    const short* __restrict__ wvB, const float* __restrict__ bv,
    float* __restrict__ out)
{
    const int orig = blockIdx.x;           // 0..255
    const int swzb = (orig & 7) * 32 + (orig >> 3);
    const int b    = swzb >> 5;
    const int qt   = swzb & 31;

    const int tid  = threadIdx.x;          // 0..511
    const int w    = tid >> 6;             // wave = head n
    const int n    = w;
    const int lane = tid & 63;
    const int h    = lane >> 5;            // lane half
    const int qc   = lane & 31;            // query column
    const int q    = qt * 32 + qc;
    const int swz  = qc & 7;

    __shared__ __align__(16) short lds[32768];   // 64 KB
    short* const Kst0 = lds;
    short* const Vst0 = lds + 4096;
    short* const Kst1 = lds + 8192;
    short* const Vst1 = lds + 12288;
    short* const Kst2 = lds + 16384;
    short* const Vst2 = lds + 20480;
    short* const Kst3 = lds + 24576;
    short* const Vst3 = lds + 28672;

    // ---- fused Q-side projection (per wave's head) ----
    bf16x8 qf[4];
    float cq;
    {
        const short* hrow = hidB + (((size_t)b * 1024) + q) * 64 + 8 * h;
        bf16x8 hq[4];
#pragma unroll
        for (int kk = 0; kk < 4; ++kk) hq[kk] = *(const bf16x8*)(hrow + 16 * kk);

        float aD[32];
#pragma unroll
        for (int ct = 0; ct < 2; ++ct) {
            f32x16 ci;
            const float* r0p = row0 + n * 64 + 32 * ct + 4 * h;
#pragma unroll
            for (int rg = 0; rg < 4; ++rg) {
                const float4 v = *(const float4*)(r0p + 8 * rg);
                ci[4 * rg + 0] = v.x; ci[4 * rg + 1] = v.y;
                ci[4 * rg + 2] = v.z; ci[4 * rg + 3] = v.w;
            }
            const short* mbase = MqBt + n * 4096 + (size_t)(32 * ct + qc) * 64 + 8 * h;
            ci = MFMA32(*(const bf16x8*)(mbase),      hq[0], ci);
            ci = MFMA32(*(const bf16x8*)(mbase + 16), hq[1], ci);
            ci = MFMA32(*(const bf16x8*)(mbase + 32), hq[2], ci);
            ci = MFMA32(*(const bf16x8*)(mbase + 48), hq[3], ci);
#pragma unroll
            for (int i = 0; i < 16; ++i) aD[16 * ct + i] = ci[i];
        }
        dlayout_to_bfrag(aD, qf);

        float part = 0.f;
#pragma unroll
        for (int kk = 0; kk < 4; ++kk) {
            const float4 v0 = *(const float4*)&vn[n * 64 + 16 * kk + 8 * h];
            const float4 v1 = *(const float4*)&vn[n * 64 + 16 * kk + 8 * h + 4];
            part += bf2f(hq[kk][0]) * v0.x + bf2f(hq[kk][1]) * v0.y +
                    bf2f(hq[kk][2]) * v0.z + bf2f(hq[kk][3]) * v0.w +
                    bf2f(hq[kk][4]) * v1.x + bf2f(hq[kk][5]) * v1.y +
                    bf2f(hq[kk][6]) * v1.z + bf2f(hq[kk][7]) * v1.w;
        }
        cq = xhalf_sum(part) + snv[n];
    }

    // posRow constants + cq fold (kt-invariant)
    float prowA[16];
    {
        const float* pr = posRow + (n * 32 + qc) * 32 + 4 * h;
#pragma unroll
        for (int rg = 0; rg < 4; ++rg) {
            const float4 v = *(const float4*)(pr + 8 * rg);
            prowA[4 * rg + 0] = v.x + cq; prowA[4 * rg + 1] = v.y + cq;
            prowA[4 * rg + 2] = v.z + cq; prowA[4 * rg + 3] = v.w + cq;
        }
    }
    const float* pcp = posCol + (n * 32 + qt) * 32;

    const short* Kbase = hidB + (size_t)b * 65536;          // [s][64] rows = keys
    const short* Vbase = VtBw + (size_t)b * 65536;          // tile-major [kt][d][64]

    // staging: 512 threads, each 1 K-chunk + 1 V-chunk (row = tid>>3, c16 = tid&7)
    const int c16  = tid & 7;
    const int srow = tid >> 3;          // 0..63
    const int woff = srow * 128 + ((c16 ^ (srow & 7)) << 4);
    const short* kp = Kbase + (size_t)srow * 64 + c16 * 8;
    const short* vp = Vbase + (size_t)srow * 64 + c16 * 8;

    float lsum = 0.f;                     // per-half partial (cross-half at end)
    f32x16 oacc[2];
#pragma unroll
    for (int dt = 0; dt < 2; ++dt)
#pragma unroll
        for (int i = 0; i < 16; ++i) oacc[dt][i] = 0.f;

    // ---- phase functions (shared math, split for cross-tile scheduling) ----
    auto qk_phase = [&](int kt, const short* Ktc_s, f32x16* sc) {
        const char* Ktc = (const char*)Ktc_s;
        const float pcv[2] = {pcp[2 * kt], pcp[2 * kt + 1]};
#pragma unroll
        for (int ct = 0; ct < 2; ++ct) {
            bf16x8 kf[4];
            const int rb = (32 * ct + qc) * 128;
#pragma unroll
            for (int k = 0; k < 4; ++k)
                kf[k] = *(const bf16x8*)(Ktc + rb + (((2 * k + h) ^ swz) << 4));
            f32x16 ci;
#pragma unroll
            for (int i = 0; i < 16; ++i) ci[i] = prowA[i] + pcv[ct];
            ci = MFMA32(kf[0], qf[0], ci);
            ci = MFMA32(kf[1], qf[1], ci);
            ci = MFMA32(kf[2], qf[2], ci);
            sc[ct] = MFMA32(kf[3], qf[3], ci);
        }
    };
    auto vf_load = [&](const short* Vtc_s, bf16x8 (*vf)[4]) {
        const char* Vtc = (const char*)Vtc_s;
#pragma unroll
        for (int dt = 0; dt < 2; ++dt) {
            const int rb = (32 * dt + qc) * 128;
#pragma unroll
            for (int ks = 0; ks < 4; ++ks)
                vf[dt][ks] = *(const bf16x8*)(Vtc + rb + (((2 * ks + h) ^ swz) << 4));
        }
    };
    auto sm_pv = [&](const f32x16* sc, const bf16x8 (*vf)[4]) {
        bf16x8 pfrag[4];
#pragma unroll
        for (int ct = 0; ct < 2; ++ct) {
            float p[16];
#pragma unroll
            for (int i = 0; i < 16; ++i) p[i] = __builtin_amdgcn_exp2f(sc[ct][i]);
            float s8[8];
#pragma unroll
            for (int i = 0; i < 8; ++i) s8[i] = p[i] + p[i + 8];
            lsum += ((s8[0] + s8[1]) + (s8[2] + s8[3])) +
                    ((s8[4] + s8[5]) + (s8[6] + s8[7]));
            dhalf_to_bfrag(p, &pfrag[2 * ct]);
        }
#pragma unroll
        for (int dt = 0; dt < 2; ++dt) {
            f32x16 oa = oacc[dt];
            oa = MFMA32(vf[dt][0], pfrag[0], oa);
            oa = MFMA32(vf[dt][1], pfrag[1], oa);
            oa = MFMA32(vf[dt][2], pfrag[2], oa);
            oacc[dt] = MFMA32(vf[dt][3], pfrag[3], oa);
        }
    };

    // prologue: stage tiles 0,1 into pair0
    {
        const float4 a0 = *(const float4*)kp;
        const float4 a1 = *(const float4*)vp;
        const float4 b0 = *(const float4*)(kp + 4096);
        const float4 b1 = *(const float4*)(vp + 4096);
        *(float4*)((char*)Kst0 + woff) = a0;
        *(float4*)((char*)Vst0 + woff) = a1;
        *(float4*)((char*)Kst1 + woff) = b0;
        *(float4*)((char*)Vst1 + woff) = b1;
    }
    __syncthreads();

    // main loop: 4 super-iters, 2 windows each; window = 2 tiles, 1 barrier
#pragma unroll 1
    for (int i = 0; i < 4; ++i) {
        const int t0 = 4 * i;
        // window A (pair0): compute t0, t0+1; stage t0+2, t0+3 -> pair1
        {
            const size_t oA = (size_t)(t0 + 2) * 4096;
            const size_t oB = (size_t)(t0 + 3) * 4096;
            const float4 ka2 = *(const float4*)(kp + oA);
            const float4 va2 = *(const float4*)(vp + oA);
            const float4 ka3 = *(const float4*)(kp + oB);
            const float4 va3 = *(const float4*)(vp + oB);
            f32x16 scA[2], scB[2];
            bf16x8 vfA[2][4], vfB[2][4];
            qk_phase(t0, Kst0, scA);
            vf_load(Vst0, vfA);
            qk_phase(t0 + 1, Kst1, scB);
            vf_load(Vst1, vfB);
            sm_pv(scA, vfA);
            sm_pv(scB, vfB);
            *(float4*)((char*)Kst2 + woff) = ka2;
            *(float4*)((char*)Vst2 + woff) = va2;
            *(float4*)((char*)Kst3 + woff) = ka3;
            *(float4*)((char*)Vst3 + woff) = va3;
            __syncthreads();
        }
        // window B (pair1): compute t0+2, t0+3; stage t0+4, t0+5 -> pair0
        if (i < 3) {
            const size_t oA = (size_t)(t0 + 4) * 4096;
            const size_t oB = (size_t)(t0 + 5) * 4096;
            const float4 ka4 = *(const float4*)(kp + oA);
            const float4 va4 = *(const float4*)(vp + oA);
            const float4 ka5 = *(const float4*)(kp + oB);
            const float4 va5 = *(const float4*)(vp + oB);
            f32x16 scA[2], scB[2];
            bf16x8 vfA[2][4], vfB[2][4];
            qk_phase(t0 + 2, Kst2, scA);
            vf_load(Vst2, vfA);
            qk_phase(t0 + 3, Kst3, scB);
            vf_load(Vst3, vfB);
            sm_pv(scA, vfA);
            sm_pv(scB, vfB);
            *(float4*)((char*)Kst0 + woff) = ka4;
            *(float4*)((char*)Vst0 + woff) = va4;
            *(float4*)((char*)Kst1 + woff) = ka5;
            *(float4*)((char*)Vst1 + woff) = va5;
            __syncthreads();
        } else {
            f32x16 scA[2], scB[2];
            bf16x8 vfA[2][4], vfB[2][4];
            qk_phase(14, Kst2, scA);
            vf_load(Vst2, vfA);
            qk_phase(15, Kst3, scB);
            vf_load(Vst3, vfB);
            sm_pv(scA, vfA);
            sm_pv(scB, vfB);
        }
    }

    // ---- fused V-projection ----
    const float inv = 1.0f / xhalf_sum(lsum);
    float hoD[32];
#pragma unroll
    for (int dt = 0; dt < 2; ++dt)
#pragma unroll
        for (int i = 0; i < 16; ++i) hoD[16 * dt + i] = oacc[dt][i] * inv;
    bf16x8 hofrag[4];
    dlayout_to_bfrag(hoD, hofrag);

    f32x16 dvacc[2];
#pragma unroll
    for (int ct = 0; ct < 2; ++ct)
#pragma unroll
        for (int i = 0; i < 16; ++i) dvacc[ct][i] = 0.f;
#pragma unroll
    for (int ct = 0; ct < 2; ++ct)
#pragma unroll
        for (int k = 0; k < 4; ++k) {
            const bf16x8 aw = *(const bf16x8*)&wvB[(size_t)(32 * ct + qc) * 512 +
                                                   n * 64 + 16 * k + 8 * h];
            dvacc[ct] = MFMA32(aw, hofrag[k], dvacc[ct]);
        }

    // cross-head sum in LDS: slot n, flat [i][lane] (bank = lane&31: 2-way, free)
    __syncthreads();                       // all waves done with K/V staging LDS
    float* cb = (float*)lds;
#pragma unroll
    for (int i = 0; i < 32; ++i)
        cb[n * 2048 + i * 64 + lane] = dvacc[i >> 4][i & 15];
    __syncthreads();

    // wave w merges reg-indices 4w..4w+3 across all 8 heads, stores f32x4.
    float s[4];
#pragma unroll
    for (int k = 0; k < 4; ++k) {
        const int i = 4 * w + k;
        float acc = 0.f;
#pragma unroll
        for (int nn = 0; nn < 8; ++nn) acc += cb[nn * 2048 + i * 64 + lane];
        s[k] = acc;
    }
    // i = 4w+k -> dv = 32*(w>>2) + 8*(w&3) + 4h + k  (k consecutive)
    const int dvb = 32 * (w >> 2) + 8 * (w & 3) + 4 * h;
    const float4 bb4 = *(const float4*)&bv[dvb];
    const int row = b * 1024 + qt * 32 + qc;
    *(float4*)&out[(size_t)row * 64 + dvb] =
        make_float4(s[0] + bb4.x, s[1] + bb4.y, s[2] + bb4.z, s[3] + bb4.w);
}

// ---------------------------------------------------------------------------
extern "C" void kernel_launch(void* const* d_in, const int* in_sizes, int n_in,
                              void* d_out, int out_size, void* d_ws, size_t ws_size,
                              hipStream_t stream)
{
    const float* hid     = (const float*)d_in[0];
    const float* row_emb = (const float*)d_in[2];
    const float* col_emb = (const float*)d_in[3];
    const float* w_row   = (const float*)d_in[4];
    const float* w_col   = (const float*)d_in[5];
    const float* w_q     = (const float*)d_in[6];
    const float* b_q     = (const float*)d_in[7];
    const float* w_k     = (const float*)d_in[8];
    const float* b_k     = (const float*)d_in[9];
    const float* w_v     = (const float*)d_in[10];
    const float* b_v     = (const float*)d_in[11];
    float* out = (float*)d_out;

    // ws layout:
    // hidB 512K sh | VtB 512K sh | MqBt 32K sh | posRow 8K f32 | posCol 8K f32 |
    // row0 512 f32 | vn 512 f32 | sn 8 f32 | wvB 32K sh
    short* hidB   = (short*)d_ws;
    short* VtBw   = hidB + (size_t)SB * SS * SC;
    short* MqBt   = VtBw + (size_t)SB * SS * SC;
    float* posRow = (float*)(MqBt + SNH * SC * SC);
    float* posCol = posRow + SNH * 32 * 32;
    float* row0   = posCol + SNH * 32 * 32;
    float* vn     = row0 + SNH * SC;
    float* snv    = vn + SNH * SC;
    short* wvB    = (short*)(snv + 8);

    prep1<<<216, 256, 0, stream>>>(row_emb, col_emb, w_row, w_col, w_v, w_q,
                                   w_k, hid, b_q, b_k,
                                   posRow, posCol, wvB, hidB, VtBw,
                                   MqBt, row0, vn, snv);
    attn_fused<<<256, 512, 0, stream>>>(hidB, VtBw, MqBt, row0, vn, snv,
                                        posRow, posCol, wvB, b_v, out);
}